// Round 1
// baseline (490.407 us; speedup 1.0000x reference)
//
#include <hip/hip_runtime.h>
#include <hip/hip_fp16.h>

#define NPTS 262144
#define FDIM 64
#define NCELL 32768  // 32^3 Morton cells

typedef float vfloat4 __attribute__((ext_vector_type(4)));

// ---------- standalone break kernel (fallback path only) ----------
__global__ __launch_bounds__(256) void break_kernel(const float* __restrict__ x,
                                                    const float* __restrict__ rays_o,
                                                    const float* __restrict__ scale,
                                                    unsigned* __restrict__ breaks) {
  const unsigned t = blockIdx.x * 256u + threadIdx.x;  // 256 blocks x 256 threads
  const float r0 = rays_o[0], r1 = rays_o[1], r2 = rays_o[2];
  const float s0 = scale[0], s1 = scale[1], s2 = scale[2];
  unsigned b1 = 0xFFFFFFFFu, b2 = 0xFFFFFFFFu;
  for (unsigned p = t; p < NPTS; p += 65536u) {
    const float dx = r0 - x[p * 3 + 0] * s0;
    const float dy = r1 - x[p * 3 + 1] * s1;
    const float dz = r2 - x[p * 3 + 2] * s2;
    const float d = sqrtf(__fadd_rn(__fadd_rn(__fmul_rn(dx, dx), __fmul_rn(dy, dy)),
                                    __fmul_rn(dz, dz)));
    if (d > 1.5f) b1 = min(b1, p);
    if (d > 2.0f) b2 = min(b2, p);
  }
#pragma unroll
  for (int o = 32; o > 0; o >>= 1) {
    b1 = min(b1, (unsigned)__shfl_down((int)b1, o, 64));
    b2 = min(b2, (unsigned)__shfl_down((int)b2, o, 64));
  }
  if ((threadIdx.x & 63) == 0) {
    atomicMin(&breaks[0], b1);
    atomicMin(&breaks[1], b2);
  }
}

// ---------- Morton cell key ----------
__device__ __forceinline__ unsigned part5(unsigned v) {
  v &= 31u;
  v = (v | (v << 8)) & 0x100Fu;
  v = (v | (v << 4)) & 0x10C3u;
  v = (v | (v << 2)) & 0x1249u;
  return v;
}

__device__ __forceinline__ unsigned cell_key(float x0, float x1, float x2) {
  const int cx = min(max((int)((x0 + 1.0f) * 16.0f), 0), 31);
  const int cy = min(max((int)((x1 + 1.0f) * 16.0f), 0), 31);
  const int cz = min(max((int)((x2 + 1.0f) * 16.0f), 0), 31);
  return part5((unsigned)cx) | (part5((unsigned)cy) << 1) | (part5((unsigned)cz) << 2);
}

// ---------- fused break-finding + histogram (single pass over x) ----------
__global__ __launch_bounds__(256) void breakhist_kernel(const float* __restrict__ x,
                                                        const float* __restrict__ rays_o,
                                                        const float* __restrict__ scale,
                                                        unsigned* __restrict__ breaks,
                                                        unsigned* __restrict__ hist) {
  const unsigned t = blockIdx.x * 256u + threadIdx.x;  // NPTS threads
  const float s0 = scale[0], s1 = scale[1], s2 = scale[2];
  const float xs0 = x[t * 3 + 0] * s0;
  const float xs1 = x[t * 3 + 1] * s1;
  const float xs2 = x[t * 3 + 2] * s2;
  const float dx = rays_o[0] - xs0;
  const float dy = rays_o[1] - xs1;
  const float dz = rays_o[2] - xs2;
  const float d = sqrtf(__fadd_rn(__fadd_rn(__fmul_rn(dx, dx), __fmul_rn(dy, dy)),
                                  __fmul_rn(dz, dz)));
  unsigned b1 = (d > 1.5f) ? t : 0xFFFFFFFFu;
  unsigned b2 = (d > 2.0f) ? t : 0xFFFFFFFFu;
#pragma unroll
  for (int o = 32; o > 0; o >>= 1) {
    b1 = min(b1, (unsigned)__shfl_down((int)b1, o, 64));
    b2 = min(b2, (unsigned)__shfl_down((int)b2, o, 64));
  }
  if ((threadIdx.x & 63) == 0) {
    atomicMin(&breaks[0], b1);
    atomicMin(&breaks[1], b2);
  }
  const unsigned key = cell_key(xs0, xs1, xs2);
  atomicAdd(&hist[key], 1u);
}

// ---------- counting-sort scan kernels ----------
// Parallel exclusive scan over NCELL entries: 128 blocks x 256 cells each.
__global__ __launch_bounds__(256) void scan1_kernel(unsigned* __restrict__ hist,
                                                    unsigned* __restrict__ partials) {
  const int cell = blockIdx.x * 256 + threadIdx.x;
  const int tid = threadIdx.x;
  const unsigned h = hist[cell];
  __shared__ unsigned ls[256];
  ls[tid] = h;
  __syncthreads();
  for (int d = 1; d < 256; d <<= 1) {
    const unsigned add = (tid >= d) ? ls[tid - d] : 0u;
    __syncthreads();
    ls[tid] += add;
    __syncthreads();
  }
  hist[cell] = ls[tid] - h;  // local exclusive prefix
  if (tid == 255) partials[blockIdx.x] = ls[255];
}

__global__ __launch_bounds__(128) void scan2_kernel(unsigned* __restrict__ partials) {
  const int tid = threadIdx.x;  // 1 block x 128
  const unsigned h = partials[tid];
  __shared__ unsigned ls[128];
  ls[tid] = h;
  __syncthreads();
  for (int d = 1; d < 128; d <<= 1) {
    const unsigned add = (tid >= d) ? ls[tid - d] : 0u;
    __syncthreads();
    ls[tid] += add;
    __syncthreads();
  }
  partials[tid] = ls[tid] - h;  // exclusive
}

// ---------- scatter: build sorted {xs0,xs1,xs2, p|level<<18} records ----------
__global__ __launch_bounds__(256) void scatter_kernel(const float* __restrict__ x,
                                                      const float* __restrict__ scale,
                                                      const unsigned* __restrict__ breaks,
                                                      unsigned* __restrict__ offs,
                                                      const unsigned* __restrict__ partials,
                                                      float4* __restrict__ xs_sorted) {
  const unsigned t = blockIdx.x * 256u + threadIdx.x;  // NPTS threads
  const float s0 = scale[0], s1 = scale[1], s2 = scale[2];
  const float xs0 = x[t * 3 + 0] * s0;
  const float xs1 = x[t * 3 + 1] * s1;
  const float xs2 = x[t * 3 + 2] * s2;
  const unsigned key = cell_key(xs0, xs1, xs2);
  const unsigned pos = atomicAdd(&offs[key], 1u) + partials[key >> 8];
  unsigned b1 = breaks[0]; if (b1 >= NPTS) b1 = 0;
  unsigned b2 = breaks[1]; if (b2 >= NPTS) b2 = 0;
  const unsigned lvl = (t < b1) ? 0u : ((t < b2) ? 1u : 2u);
  float4 v;
  v.x = xs0; v.y = xs1; v.z = xs2;
  v.w = __uint_as_float(t | (lvl << 18));  // NPTS = 2^18 fits in 18 bits
  xs_sorted[pos] = v;
}

// ---------- fused transpose: 9x [C][S][S] fp32 -> [S*S][C] fp16 ----------
// No LDS. Thread = (4 pixels, 8 channels): 8x float4 channel-strided reads
// (each load instr = 8 c8-groups x 8 lanes x 16B = eight full 128B lines),
// register convert, 4x uint4 writes (full 128B lines per slot-group).
#define TPIX 128  // pixels per block: 256 threads / 8 c8 * 4 px

struct TransposeArgs {
  const float* src[9];
  __half* dst[9];
  int tile_hi[9];  // inclusive prefix sum of tiles per plane
  int SS[9];
};

union H8 { uint4 u; __half h[8]; };

__global__ __launch_bounds__(256) void transpose_all(TransposeArgs a) {
  const int tile = blockIdx.x;
  int pi = 0;
#pragma unroll
  for (int i = 0; i < 9; ++i) {
    if (tile >= a.tile_hi[i]) pi = i + 1;
  }
  const int lo = (pi == 0) ? 0 : a.tile_hi[pi - 1];
  const float* __restrict__ src = a.src[pi];
  __half* __restrict__ dst = a.dst[pi];
  const size_t SS = (size_t)a.SS[pi];

  const int t = threadIdx.x;
  const int slot = t >> 3;  // 0..31
  const int c8 = t & 7;     // 0..7
  const size_t p0 = (size_t)(tile - lo) * TPIX + (size_t)slot * 4;
  const float* __restrict__ srcb = src + (size_t)(c8 * 8) * SS + p0;

  H8 h[4];
#pragma unroll
  for (int k = 0; k < 8; ++k) {
    const float4 v = *(const float4*)(srcb + (size_t)k * SS);
    h[0].h[k] = __float2half(v.x);
    h[1].h[k] = __float2half(v.y);
    h[2].h[k] = __float2half(v.z);
    h[3].h[k] = __float2half(v.w);
  }
#pragma unroll
  for (int r = 0; r < 4; ++r) {
    *(uint4*)(dst + (p0 + (size_t)r) * FDIM + c8 * 8) = h[r].u;
  }
}

// ---------- bilinear sampling helpers ----------
__device__ __forceinline__ void bilinear_weights(int W, float cx, float cy,
                                                 float& w00, float& w01, float& w10, float& w11,
                                                 int& xc0, int& xc1, int& yc0, int& yc1) {
  const float Wm1 = (float)(W - 1);
  const float fx = (cx + 1.0f) * 0.5f * Wm1;
  const float fy = (cy + 1.0f) * 0.5f * Wm1;
  const float x0f = floorf(fx), y0f = floorf(fy);
  const float wx = fx - x0f, wy = fy - y0f;
  const int ix = (int)x0f, iy = (int)y0f;
  const int ix1 = ix + 1, iy1 = iy + 1;
  const bool vx0 = (ix >= 0) && (ix < W);
  const bool vx1 = (ix1 >= 0) && (ix1 < W);
  const bool vy0 = (iy >= 0) && (iy < W);
  const bool vy1 = (iy1 >= 0) && (iy1 < W);
  xc0 = min(max(ix, 0), W - 1);
  xc1 = min(max(ix1, 0), W - 1);
  yc0 = min(max(iy, 0), W - 1);
  yc1 = min(max(iy1, 0), W - 1);
  w00 = (1.0f - wx) * (1.0f - wy) * (float)(vx0 && vy0);
  w01 = wx * (1.0f - wy) * (float)(vx1 && vy0);
  w10 = (1.0f - wx) * wy * (float)(vx0 && vy1);
  w11 = wx * wy * (float)(vx1 && vy1);
}

__device__ __forceinline__ void sample8_t(const __half* __restrict__ pl, int W,
                                          float cx, float cy, int j8, float acc[8]) {
  float w00, w01, w10, w11;
  int xc0, xc1, yc0, yc1;
  bilinear_weights(W, cx, cy, w00, w01, w10, w11, xc0, xc1, yc0, yc1);
  const __half* b00 = pl + ((size_t)(yc0 * W + xc0) * FDIM + j8);
  const __half* b01 = pl + ((size_t)(yc0 * W + xc1) * FDIM + j8);
  const __half* b10 = pl + ((size_t)(yc1 * W + xc0) * FDIM + j8);
  const __half* b11 = pl + ((size_t)(yc1 * W + xc1) * FDIM + j8);
  H8 v00, v01, v10, v11;
  v00.u = *(const uint4*)b00;
  v01.u = *(const uint4*)b01;
  v10.u = *(const uint4*)b10;
  v11.u = *(const uint4*)b11;
#pragma unroll
  for (int k = 0; k < 8; ++k) {
    acc[k] += w00 * __half2float(v00.h[k]) + w01 * __half2float(v01.h[k]) +
              w10 * __half2float(v10.h[k]) + w11 * __half2float(v11.h[k]);
  }
}

__device__ __forceinline__ void sample8_d(const float* __restrict__ pl, int W,
                                          float cx, float cy, int j8, float acc[8]) {
  float w00, w01, w10, w11;
  int xc0, xc1, yc0, yc1;
  bilinear_weights(W, cx, cy, w00, w01, w10, w11, xc0, xc1, yc0, yc1);
  const size_t SS = (size_t)W * W;
  const int i00 = yc0 * W + xc0, i01 = yc0 * W + xc1;
  const int i10 = yc1 * W + xc0, i11 = yc1 * W + xc1;
#pragma unroll
  for (int k = 0; k < 8; ++k) {
    const size_t co = (size_t)(j8 + k) * SS;
    acc[k] += w00 * pl[co + i00] + w01 * pl[co + i01] +
              w10 * pl[co + i10] + w11 * pl[co + i11];
  }
}

struct PlanesH { const __half* p[9]; };
struct PlanesF { const float* p[9]; };

// ---------- main sampling kernel (fp16 transposed planes, sorted records) ----------
#define SAMPLE_BLOCKS (NPTS * 8 / 256)  // 8192
#define XCD_CHUNK (SAMPLE_BLOCKS / 8)   // 1024

__global__ __launch_bounds__(256) void sample_kernel(const float4* __restrict__ xs_sorted,
                                                     PlanesH tp, float* __restrict__ out) {
  // XCD-aware bijective swizzle: each XCD gets a contiguous chunk of the
  // Morton-sorted point stream -> cross-block L2 reuse lands on ONE L2.
  const unsigned b = blockIdx.x;
  const unsigned sb = (b & 7u) * XCD_CHUNK + (b >> 3);
  const int t = (int)(sb * 256u + threadIdx.x);
  const int slot = t >> 3;
  const int j8 = (t & 7) * 8;
  const float4 ps = xs_sorted[slot];  // one 16B load/point, coalesced + broadcast
  const unsigned w = __float_as_uint(ps.w);
  const int p = (int)(w & 0x3FFFFu);
  const int level = (int)(w >> 18);
  float acc[8];
#pragma unroll
  for (int k = 0; k < 8; ++k) acc[k] = 0.0f;
  sample8_t(tp.p[0], 512, ps.x, ps.y, j8, acc);  // xy: (x,y)
  sample8_t(tp.p[1], 512, ps.y, ps.z, j8, acc);  // yz: (y,z)
  sample8_t(tp.p[2], 512, ps.x, ps.z, j8, acc);  // xz: (x,z)
  if (level >= 1) {
    sample8_t(tp.p[3], 256, ps.x, ps.y, j8, acc);
    sample8_t(tp.p[4], 256, ps.y, ps.z, j8, acc);
    sample8_t(tp.p[5], 256, ps.x, ps.z, j8, acc);
  }
  if (level >= 2) {
    sample8_t(tp.p[6], 128, ps.x, ps.y, j8, acc);
    sample8_t(tp.p[7], 128, ps.y, ps.z, j8, acc);
    sample8_t(tp.p[8], 128, ps.x, ps.z, j8, acc);
  }
  float* o = out + (size_t)p * FDIM + j8;
  vfloat4 lo = {acc[0], acc[1], acc[2], acc[3]};
  vfloat4 hi = {acc[4], acc[5], acc[6], acc[7]};
  __builtin_nontemporal_store(lo, (vfloat4*)o);
  __builtin_nontemporal_store(hi, (vfloat4*)(o + 4));
}

// ---------- fallback: sample directly from fp32 [C][H][W], unsorted ----------
__global__ __launch_bounds__(256) void sample_kernel_direct(const float* __restrict__ x,
                                                            const float* __restrict__ scale,
                                                            const unsigned* __restrict__ breaks,
                                                            PlanesF tp, float* __restrict__ out) {
  const int t = blockIdx.x * 256 + threadIdx.x;
  const int p = t >> 3;
  const int j8 = (t & 7) * 8;
  const float s0 = scale[0], s1 = scale[1], s2 = scale[2];
  const float xs0 = x[p * 3 + 0] * s0;
  const float xs1 = x[p * 3 + 1] * s1;
  const float xs2 = x[p * 3 + 2] * s2;
  unsigned b1 = breaks[0]; if (b1 >= NPTS) b1 = 0;
  unsigned b2 = breaks[1]; if (b2 >= NPTS) b2 = 0;
  const unsigned pu = (unsigned)p;
  const int level = (pu < b1) ? 0 : ((pu < b2) ? 1 : 2);
  float acc[8];
#pragma unroll
  for (int k = 0; k < 8; ++k) acc[k] = 0.0f;
  sample8_d(tp.p[0], 512, xs0, xs1, j8, acc);
  sample8_d(tp.p[1], 512, xs1, xs2, j8, acc);
  sample8_d(tp.p[2], 512, xs0, xs2, j8, acc);
  if (level >= 1) {
    sample8_d(tp.p[3], 256, xs0, xs1, j8, acc);
    sample8_d(tp.p[4], 256, xs1, xs2, j8, acc);
    sample8_d(tp.p[5], 256, xs0, xs2, j8, acc);
  }
  if (level >= 2) {
    sample8_d(tp.p[6], 128, xs0, xs1, j8, acc);
    sample8_d(tp.p[7], 128, xs1, xs2, j8, acc);
    sample8_d(tp.p[8], 128, xs0, xs2, j8, acc);
  }
  float4* o4 = (float4*)(out + (size_t)p * FDIM + j8);
  o4[0] = make_float4(acc[0], acc[1], acc[2], acc[3]);
  o4[1] = make_float4(acc[4], acc[5], acc[6], acc[7]);
}

extern "C" void kernel_launch(void* const* d_in, const int* in_sizes, int n_in,
                              void* d_out, int out_size, void* d_ws, size_t ws_size,
                              hipStream_t stream) {
  const float* x = (const float*)d_in[0];
  const float* rays_o = (const float*)d_in[1];
  const float* scale = (const float*)d_in[2];
  const float* pl32[9];
  for (int i = 0; i < 9; ++i) pl32[i] = (const float*)d_in[3 + i];
  float* out = (float*)d_out;

  unsigned char* ws = (unsigned char*)d_ws;
  // ws layout: breaks @0 (8B) | partials @128 (512B) | hist @1024 (128 KB) |
  //            xs_sorted @132096 (4 MB) | planes @4326400
  unsigned* breaks = (unsigned*)ws;
  unsigned* partials = (unsigned*)(ws + 128);
  unsigned* hist = (unsigned*)(ws + 1024);
  float4* xs_sorted = (float4*)(ws + 1024 + NCELL * 4);
  const size_t planes_off = 1024 + (size_t)NCELL * 4 + (size_t)NPTS * 16;

  (void)hipMemsetAsync(d_ws, 0xFF, 8, stream);  // breaks sentinel

  const int Ss[3] = {512, 256, 128};
  size_t need = planes_off;
  for (int l = 0; l < 3; ++l) need += 3 * (size_t)Ss[l] * Ss[l] * FDIM * sizeof(__half);

  if (ws_size >= need) {
    // spatial counting sort (parallel scan, scan3 folded into scatter)
    (void)hipMemsetAsync(hist, 0, NCELL * 4, stream);
    breakhist_kernel<<<NPTS / 256, 256, 0, stream>>>(x, rays_o, scale, breaks, hist);
    scan1_kernel<<<NCELL / 256, 256, 0, stream>>>(hist, partials);
    scan2_kernel<<<1, 128, 0, stream>>>(partials);
    scatter_kernel<<<NPTS / 256, 256, 0, stream>>>(x, scale, breaks, hist, partials, xs_sorted);

    PlanesH tp;
    TransposeArgs ta;
    size_t off = planes_off;
    int tiles_acc = 0;
    for (int l = 0; l < 3; ++l) {
      const int S = Ss[l];
      const int SS = S * S;
      for (int o = 0; o < 3; ++o) {
        const int i = l * 3 + o;
        __half* dst = (__half*)(ws + off);
        tp.p[i] = dst;
        ta.src[i] = pl32[i];
        ta.dst[i] = dst;
        ta.SS[i] = SS;
        tiles_acc += SS / TPIX;
        ta.tile_hi[i] = tiles_acc;
        off += (size_t)SS * FDIM * sizeof(__half);
      }
    }
    transpose_all<<<tiles_acc, 256, 0, stream>>>(ta);
    sample_kernel<<<SAMPLE_BLOCKS, 256, 0, stream>>>(xs_sorted, tp, out);
  } else {
    break_kernel<<<256, 256, 0, stream>>>(x, rays_o, scale, breaks);
    PlanesF tf;
    for (int i = 0; i < 9; ++i) tf.p[i] = pl32[i];
    sample_kernel_direct<<<(NPTS * 8) / 256, 256, 0, stream>>>(x, scale, breaks, tf, out);
  }
}

// Round 2
// 486.748 us; speedup vs baseline: 1.0075x; 1.0075x over previous
//
#include <hip/hip_runtime.h>
#include <hip/hip_fp16.h>

#define NPTS 262144
#define FDIM 64
#define NCELL 4096  // 16^3 Morton cells, avg 64 pts/cell

typedef float vfloat4 __attribute__((ext_vector_type(4)));

// ---------- standalone break kernel (fallback path only) ----------
__global__ __launch_bounds__(256) void break_kernel(const float* __restrict__ x,
                                                    const float* __restrict__ rays_o,
                                                    const float* __restrict__ scale,
                                                    unsigned* __restrict__ breaks) {
  const unsigned t = blockIdx.x * 256u + threadIdx.x;
  const float r0 = rays_o[0], r1 = rays_o[1], r2 = rays_o[2];
  const float s0 = scale[0], s1 = scale[1], s2 = scale[2];
  unsigned b1 = 0xFFFFFFFFu, b2 = 0xFFFFFFFFu;
  for (unsigned p = t; p < NPTS; p += 65536u) {
    const float dx = r0 - x[p * 3 + 0] * s0;
    const float dy = r1 - x[p * 3 + 1] * s1;
    const float dz = r2 - x[p * 3 + 2] * s2;
    const float d = sqrtf(__fadd_rn(__fadd_rn(__fmul_rn(dx, dx), __fmul_rn(dy, dy)),
                                    __fmul_rn(dz, dz)));
    if (d > 1.5f) b1 = min(b1, p);
    if (d > 2.0f) b2 = min(b2, p);
  }
#pragma unroll
  for (int o = 32; o > 0; o >>= 1) {
    b1 = min(b1, (unsigned)__shfl_down((int)b1, o, 64));
    b2 = min(b2, (unsigned)__shfl_down((int)b2, o, 64));
  }
  if ((threadIdx.x & 63) == 0) {
    atomicMin(&breaks[0], b1);
    atomicMin(&breaks[1], b2);
  }
}

// ---------- Morton cell key (16^3) ----------
__device__ __forceinline__ unsigned part4(unsigned v) {
  v &= 15u;
  v = (v | (v << 4)) & 0x0C3u;  // b3b2 @7:6, b1b0 @1:0
  v = (v | (v << 2)) & 0x249u;  // b3@9 b2@6 b1@3 b0@0
  return v;
}

__device__ __forceinline__ unsigned cell_key(float x0, float x1, float x2) {
  const int cx = min(max((int)((x0 + 1.0f) * 8.0f), 0), 15);
  const int cy = min(max((int)((x1 + 1.0f) * 8.0f), 0), 15);
  const int cz = min(max((int)((x2 + 1.0f) * 8.0f), 0), 15);
  return part4((unsigned)cx) | (part4((unsigned)cy) << 1) | (part4((unsigned)cz) << 2);
}

// ---------- fused break-finding + histogram (single pass over x) ----------
__global__ __launch_bounds__(256) void breakhist_kernel(const float* __restrict__ x,
                                                        const float* __restrict__ rays_o,
                                                        const float* __restrict__ scale,
                                                        unsigned* __restrict__ breaks,
                                                        unsigned* __restrict__ hist) {
  const unsigned t = blockIdx.x * 256u + threadIdx.x;  // NPTS threads
  const float s0 = scale[0], s1 = scale[1], s2 = scale[2];
  const float xs0 = x[t * 3 + 0] * s0;
  const float xs1 = x[t * 3 + 1] * s1;
  const float xs2 = x[t * 3 + 2] * s2;
  const float dx = rays_o[0] - xs0;
  const float dy = rays_o[1] - xs1;
  const float dz = rays_o[2] - xs2;
  const float d = sqrtf(__fadd_rn(__fadd_rn(__fmul_rn(dx, dx), __fmul_rn(dy, dy)),
                                  __fmul_rn(dz, dz)));
  unsigned b1 = (d > 1.5f) ? t : 0xFFFFFFFFu;
  unsigned b2 = (d > 2.0f) ? t : 0xFFFFFFFFu;
#pragma unroll
  for (int o = 32; o > 0; o >>= 1) {
    b1 = min(b1, (unsigned)__shfl_down((int)b1, o, 64));
    b2 = min(b2, (unsigned)__shfl_down((int)b2, o, 64));
  }
  if ((threadIdx.x & 63) == 0) {
    atomicMin(&breaks[0], b1);
    atomicMin(&breaks[1], b2);
  }
  const unsigned key = cell_key(xs0, xs1, xs2);
  atomicAdd(&hist[key], 1u);
}

// ---------- single-block exclusive scan over NCELL=4096 entries ----------
__global__ __launch_bounds__(1024) void scan_kernel(unsigned* __restrict__ hist) {
  const int tid = threadIdx.x;  // 1 block x 1024, 4 cells/thread
  uint4 h = ((uint4*)hist)[tid];
  const unsigned i0 = h.x;
  const unsigned i1 = i0 + h.y;
  const unsigned i2 = i1 + h.z;
  const unsigned i3 = i2 + h.w;
  __shared__ unsigned ls[1024];
  ls[tid] = i3;
  __syncthreads();
  for (int d = 1; d < 1024; d <<= 1) {
    const unsigned add = (tid >= d) ? ls[tid - d] : 0u;
    __syncthreads();
    ls[tid] += add;
    __syncthreads();
  }
  const unsigned base = ls[tid] - i3;  // exclusive prefix of this thread's group
  uint4 o;
  o.x = base;
  o.y = base + i0;
  o.z = base + i1;
  o.w = base + i2;
  ((uint4*)hist)[tid] = o;  // hist now holds global exclusive bases
}

// ---------- scatter: build sorted {xs0,xs1,xs2, p|level<<18} records ----------
__global__ __launch_bounds__(256) void scatter_kernel(const float* __restrict__ x,
                                                      const float* __restrict__ scale,
                                                      const unsigned* __restrict__ breaks,
                                                      unsigned* __restrict__ offs,
                                                      float4* __restrict__ xs_sorted) {
  const unsigned t = blockIdx.x * 256u + threadIdx.x;  // NPTS threads
  const float s0 = scale[0], s1 = scale[1], s2 = scale[2];
  const float xs0 = x[t * 3 + 0] * s0;
  const float xs1 = x[t * 3 + 1] * s1;
  const float xs2 = x[t * 3 + 2] * s2;
  const unsigned key = cell_key(xs0, xs1, xs2);
  const unsigned pos = atomicAdd(&offs[key], 1u);  // global position directly
  unsigned b1 = breaks[0]; if (b1 >= NPTS) b1 = 0;
  unsigned b2 = breaks[1]; if (b2 >= NPTS) b2 = 0;
  const unsigned lvl = (t < b1) ? 0u : ((t < b2) ? 1u : 2u);
  float4 v;
  v.x = xs0; v.y = xs1; v.z = xs2;
  v.w = __uint_as_float(t | (lvl << 18));  // NPTS = 2^18 fits in 18 bits
  xs_sorted[pos] = v;
}

// ---------- fused transpose: 9x [C][S][S] fp32 -> [S*S][C] fp16 ----------
// No LDS. Thread = (4 pixels, 8 channels). The 997-swizzle spreads concurrent
// blocks' pixel phases uniformly over the plane: all 64 channel streams of a
// block share one phase mod the 1 MB channel stride, so without the swizzle
// concurrent blocks cluster onto a narrow band of HBM channels.
#define TPIX 128  // pixels per block

struct TransposeArgs {
  const float* src[9];
  __half* dst[9];
  int tile_hi[9];  // inclusive prefix sum of tiles per plane
  int SS[9];
};

union H8 { uint4 u; __half h[8]; };

__global__ __launch_bounds__(256) void transpose_all(TransposeArgs a) {
  const int tile = blockIdx.x;
  int pi = 0;
#pragma unroll
  for (int i = 0; i < 9; ++i) {
    if (tile >= a.tile_hi[i]) pi = i + 1;
  }
  const int lo = (pi == 0) ? 0 : a.tile_hi[pi - 1];
  const float* __restrict__ src = a.src[pi];
  __half* __restrict__ dst = a.dst[pi];
  const size_t SS = (size_t)a.SS[pi];

  // bijective tile scatter within the plane (997 odd -> invertible mod 2^k)
  const int ntm = (int)(SS / TPIX) - 1;
  const int tl = ((tile - lo) * 997) & ntm;

  const int t = threadIdx.x;
  const int slot = t >> 3;  // 0..31
  const int c8 = t & 7;     // 0..7
  const size_t p0 = (size_t)tl * TPIX + (size_t)slot * 4;
  const float* __restrict__ srcb = src + (size_t)(c8 * 8) * SS + p0;

  H8 h[4];
#pragma unroll
  for (int k = 0; k < 8; ++k) {
    const float4 v = *(const float4*)(srcb + (size_t)k * SS);
    h[0].h[k] = __float2half(v.x);
    h[1].h[k] = __float2half(v.y);
    h[2].h[k] = __float2half(v.z);
    h[3].h[k] = __float2half(v.w);
  }
#pragma unroll
  for (int r = 0; r < 4; ++r) {
    *(uint4*)(dst + (p0 + (size_t)r) * FDIM + c8 * 8) = h[r].u;
  }
}

// ---------- bilinear sampling helpers ----------
__device__ __forceinline__ void bilinear_weights(int W, float cx, float cy,
                                                 float& w00, float& w01, float& w10, float& w11,
                                                 int& xc0, int& xc1, int& yc0, int& yc1) {
  const float Wm1 = (float)(W - 1);
  const float fx = (cx + 1.0f) * 0.5f * Wm1;
  const float fy = (cy + 1.0f) * 0.5f * Wm1;
  const float x0f = floorf(fx), y0f = floorf(fy);
  const float wx = fx - x0f, wy = fy - y0f;
  const int ix = (int)x0f, iy = (int)y0f;
  const int ix1 = ix + 1, iy1 = iy + 1;
  const bool vx0 = (ix >= 0) && (ix < W);
  const bool vx1 = (ix1 >= 0) && (ix1 < W);
  const bool vy0 = (iy >= 0) && (iy < W);
  const bool vy1 = (iy1 >= 0) && (iy1 < W);
  xc0 = min(max(ix, 0), W - 1);
  xc1 = min(max(ix1, 0), W - 1);
  yc0 = min(max(iy, 0), W - 1);
  yc1 = min(max(iy1, 0), W - 1);
  w00 = (1.0f - wx) * (1.0f - wy) * (float)(vx0 && vy0);
  w01 = wx * (1.0f - wy) * (float)(vx1 && vy0);
  w10 = (1.0f - wx) * wy * (float)(vx0 && vy1);
  w11 = wx * wy * (float)(vx1 && vy1);
}

__device__ __forceinline__ void sample8_t(const __half* __restrict__ pl, int W,
                                          float cx, float cy, int j8, float acc[8]) {
  float w00, w01, w10, w11;
  int xc0, xc1, yc0, yc1;
  bilinear_weights(W, cx, cy, w00, w01, w10, w11, xc0, xc1, yc0, yc1);
  const __half* b00 = pl + ((size_t)(yc0 * W + xc0) * FDIM + j8);
  const __half* b01 = pl + ((size_t)(yc0 * W + xc1) * FDIM + j8);
  const __half* b10 = pl + ((size_t)(yc1 * W + xc0) * FDIM + j8);
  const __half* b11 = pl + ((size_t)(yc1 * W + xc1) * FDIM + j8);
  H8 v00, v01, v10, v11;
  v00.u = *(const uint4*)b00;
  v01.u = *(const uint4*)b01;
  v10.u = *(const uint4*)b10;
  v11.u = *(const uint4*)b11;
#pragma unroll
  for (int k = 0; k < 8; ++k) {
    acc[k] += w00 * __half2float(v00.h[k]) + w01 * __half2float(v01.h[k]) +
              w10 * __half2float(v10.h[k]) + w11 * __half2float(v11.h[k]);
  }
}

__device__ __forceinline__ void sample8_d(const float* __restrict__ pl, int W,
                                          float cx, float cy, int j8, float acc[8]) {
  float w00, w01, w10, w11;
  int xc0, xc1, yc0, yc1;
  bilinear_weights(W, cx, cy, w00, w01, w10, w11, xc0, xc1, yc0, yc1);
  const size_t SS = (size_t)W * W;
  const int i00 = yc0 * W + xc0, i01 = yc0 * W + xc1;
  const int i10 = yc1 * W + xc0, i11 = yc1 * W + xc1;
#pragma unroll
  for (int k = 0; k < 8; ++k) {
    const size_t co = (size_t)(j8 + k) * SS;
    acc[k] += w00 * pl[co + i00] + w01 * pl[co + i01] +
              w10 * pl[co + i10] + w11 * pl[co + i11];
  }
}

struct PlanesH { const __half* p[9]; };
struct PlanesF { const float* p[9]; };

// ---------- main sampling kernel (fp16 transposed planes, sorted records) ----------
#define SAMPLE_BLOCKS (NPTS * 8 / 256)  // 8192
#define XCD_CHUNK (SAMPLE_BLOCKS / 8)   // 1024

__global__ __launch_bounds__(256) void sample_kernel(const float4* __restrict__ xs_sorted,
                                                     PlanesH tp, float* __restrict__ out) {
  const unsigned b = blockIdx.x;
  const unsigned sb = (b & 7u) * XCD_CHUNK + (b >> 3);  // XCD-aware bijective swizzle
  const int t = (int)(sb * 256u + threadIdx.x);
  const int slot = t >> 3;
  const int j8 = (t & 7) * 8;
  const float4 ps = xs_sorted[slot];  // one 16B load/point, coalesced + broadcast
  const unsigned w = __float_as_uint(ps.w);
  const int p = (int)(w & 0x3FFFFu);
  const int level = (int)(w >> 18);
  float acc[8];
#pragma unroll
  for (int k = 0; k < 8; ++k) acc[k] = 0.0f;
  sample8_t(tp.p[0], 512, ps.x, ps.y, j8, acc);  // xy: (x,y)
  sample8_t(tp.p[1], 512, ps.y, ps.z, j8, acc);  // yz: (y,z)
  sample8_t(tp.p[2], 512, ps.x, ps.z, j8, acc);  // xz: (x,z)
  if (level >= 1) {
    sample8_t(tp.p[3], 256, ps.x, ps.y, j8, acc);
    sample8_t(tp.p[4], 256, ps.y, ps.z, j8, acc);
    sample8_t(tp.p[5], 256, ps.x, ps.z, j8, acc);
  }
  if (level >= 2) {
    sample8_t(tp.p[6], 128, ps.x, ps.y, j8, acc);
    sample8_t(tp.p[7], 128, ps.y, ps.z, j8, acc);
    sample8_t(tp.p[8], 128, ps.x, ps.z, j8, acc);
  }
  float* o = out + (size_t)p * FDIM + j8;
  vfloat4 lo = {acc[0], acc[1], acc[2], acc[3]};
  vfloat4 hi = {acc[4], acc[5], acc[6], acc[7]};
  __builtin_nontemporal_store(lo, (vfloat4*)o);
  __builtin_nontemporal_store(hi, (vfloat4*)(o + 4));
}

// ---------- fallback: sample directly from fp32 [C][H][W], unsorted ----------
__global__ __launch_bounds__(256) void sample_kernel_direct(const float* __restrict__ x,
                                                            const float* __restrict__ scale,
                                                            const unsigned* __restrict__ breaks,
                                                            PlanesF tp, float* __restrict__ out) {
  const int t = blockIdx.x * 256 + threadIdx.x;
  const int p = t >> 3;
  const int j8 = (t & 7) * 8;
  const float s0 = scale[0], s1 = scale[1], s2 = scale[2];
  const float xs0 = x[p * 3 + 0] * s0;
  const float xs1 = x[p * 3 + 1] * s1;
  const float xs2 = x[p * 3 + 2] * s2;
  unsigned b1 = breaks[0]; if (b1 >= NPTS) b1 = 0;
  unsigned b2 = breaks[1]; if (b2 >= NPTS) b2 = 0;
  const unsigned pu = (unsigned)p;
  const int level = (pu < b1) ? 0 : ((pu < b2) ? 1 : 2);
  float acc[8];
#pragma unroll
  for (int k = 0; k < 8; ++k) acc[k] = 0.0f;
  sample8_d(tp.p[0], 512, xs0, xs1, j8, acc);
  sample8_d(tp.p[1], 512, xs1, xs2, j8, acc);
  sample8_d(tp.p[2], 512, xs0, xs2, j8, acc);
  if (level >= 1) {
    sample8_d(tp.p[3], 256, xs0, xs1, j8, acc);
    sample8_d(tp.p[4], 256, xs1, xs2, j8, acc);
    sample8_d(tp.p[5], 256, xs0, xs2, j8, acc);
  }
  if (level >= 2) {
    sample8_d(tp.p[6], 128, xs0, xs1, j8, acc);
    sample8_d(tp.p[7], 128, xs1, xs2, j8, acc);
    sample8_d(tp.p[8], 128, xs0, xs2, j8, acc);
  }
  float4* o4 = (float4*)(out + (size_t)p * FDIM + j8);
  o4[0] = make_float4(acc[0], acc[1], acc[2], acc[3]);
  o4[1] = make_float4(acc[4], acc[5], acc[6], acc[7]);
}

extern "C" void kernel_launch(void* const* d_in, const int* in_sizes, int n_in,
                              void* d_out, int out_size, void* d_ws, size_t ws_size,
                              hipStream_t stream) {
  const float* x = (const float*)d_in[0];
  const float* rays_o = (const float*)d_in[1];
  const float* scale = (const float*)d_in[2];
  const float* pl32[9];
  for (int i = 0; i < 9; ++i) pl32[i] = (const float*)d_in[3 + i];
  float* out = (float*)d_out;

  unsigned char* ws = (unsigned char*)d_ws;
  // ws layout: breaks @0 (8B) | hist @1024 (16 KB) | xs_sorted @17408 (4 MB) | planes
  unsigned* breaks = (unsigned*)ws;
  unsigned* hist = (unsigned*)(ws + 1024);
  float4* xs_sorted = (float4*)(ws + 1024 + NCELL * 4);
  const size_t planes_off = 1024 + (size_t)NCELL * 4 + (size_t)NPTS * 16;

  (void)hipMemsetAsync(d_ws, 0xFF, 8, stream);  // breaks sentinel

  const int Ss[3] = {512, 256, 128};
  size_t need = planes_off;
  for (int l = 0; l < 3; ++l) need += 3 * (size_t)Ss[l] * Ss[l] * FDIM * sizeof(__half);

  if (ws_size >= need) {
    (void)hipMemsetAsync(hist, 0, NCELL * 4, stream);
    breakhist_kernel<<<NPTS / 256, 256, 0, stream>>>(x, rays_o, scale, breaks, hist);
    scan_kernel<<<1, 1024, 0, stream>>>(hist);
    scatter_kernel<<<NPTS / 256, 256, 0, stream>>>(x, scale, breaks, hist, xs_sorted);

    PlanesH tp;
    TransposeArgs ta;
    size_t off = planes_off;
    int tiles_acc = 0;
    for (int l = 0; l < 3; ++l) {
      const int S = Ss[l];
      const int SS = S * S;
      for (int o = 0; o < 3; ++o) {
        const int i = l * 3 + o;
        __half* dst = (__half*)(ws + off);
        tp.p[i] = dst;
        ta.src[i] = pl32[i];
        ta.dst[i] = dst;
        ta.SS[i] = SS;
        tiles_acc += SS / TPIX;
        ta.tile_hi[i] = tiles_acc;
        off += (size_t)SS * FDIM * sizeof(__half);
      }
    }
    transpose_all<<<tiles_acc, 256, 0, stream>>>(ta);
    sample_kernel<<<SAMPLE_BLOCKS, 256, 0, stream>>>(xs_sorted, tp, out);
  } else {
    break_kernel<<<256, 256, 0, stream>>>(x, rays_o, scale, breaks);
    PlanesF tf;
    for (int i = 0; i < 9; ++i) tf.p[i] = pl32[i];
    sample_kernel_direct<<<(NPTS * 8) / 256, 256, 0, stream>>>(x, scale, breaks, tf, out);
  }
}

// Round 3
// 474.927 us; speedup vs baseline: 1.0326x; 1.0249x over previous
//
#include <hip/hip_runtime.h>
#include <hip/hip_fp16.h>

#define NPTS 262144
#define FDIM 64
#define NCELL 4096  // 16^3 Morton cells, avg 64 pts/cell

typedef float vfloat4 __attribute__((ext_vector_type(4)));

// ---------- standalone break kernel (fallback path only) ----------
__global__ __launch_bounds__(256) void break_kernel(const float* __restrict__ x,
                                                    const float* __restrict__ rays_o,
                                                    const float* __restrict__ scale,
                                                    unsigned* __restrict__ breaks) {
  const unsigned t = blockIdx.x * 256u + threadIdx.x;
  const float r0 = rays_o[0], r1 = rays_o[1], r2 = rays_o[2];
  const float s0 = scale[0], s1 = scale[1], s2 = scale[2];
  unsigned b1 = 0xFFFFFFFFu, b2 = 0xFFFFFFFFu;
  for (unsigned p = t; p < NPTS; p += 65536u) {
    const float dx = r0 - x[p * 3 + 0] * s0;
    const float dy = r1 - x[p * 3 + 1] * s1;
    const float dz = r2 - x[p * 3 + 2] * s2;
    const float d = sqrtf(__fadd_rn(__fadd_rn(__fmul_rn(dx, dx), __fmul_rn(dy, dy)),
                                    __fmul_rn(dz, dz)));
    if (d > 1.5f) b1 = min(b1, p);
    if (d > 2.0f) b2 = min(b2, p);
  }
#pragma unroll
  for (int o = 32; o > 0; o >>= 1) {
    b1 = min(b1, (unsigned)__shfl_down((int)b1, o, 64));
    b2 = min(b2, (unsigned)__shfl_down((int)b2, o, 64));
  }
  if ((threadIdx.x & 63) == 0) {
    atomicMin(&breaks[0], b1);
    atomicMin(&breaks[1], b2);
  }
}

// ---------- Morton cell key (16^3) ----------
__device__ __forceinline__ unsigned part4(unsigned v) {
  v &= 15u;
  v = (v | (v << 4)) & 0x0C3u;
  v = (v | (v << 2)) & 0x249u;
  return v;
}

__device__ __forceinline__ unsigned cell_key(float x0, float x1, float x2) {
  const int cx = min(max((int)((x0 + 1.0f) * 8.0f), 0), 15);
  const int cy = min(max((int)((x1 + 1.0f) * 8.0f), 0), 15);
  const int cz = min(max((int)((x2 + 1.0f) * 8.0f), 0), 15);
  return part4((unsigned)cx) | (part4((unsigned)cy) << 1) | (part4((unsigned)cz) << 2);
}

// ---------- fused: [0,NB_BH) break+hist blocks, rest transpose ----------
// breakhist and transpose are independent; fusing hides the 3 MB x-pass
// under the transpose's ~107 us of memory time and saves a dispatch gap.
// breaks use inverted atomicMax (store NPTS-t vs 0-init) so breaks+hist
// share ONE zero-memset.
#define NB_BH (NPTS / 256)  // 1024 breakhist blocks
#define TPIX 128            // pixels per transpose block

struct TransposeArgs {
  const float* src[9];
  __half* dst[9];
  int tile_hi[9];  // inclusive prefix sum of tiles per plane
  int SS[9];
};

union H8 { uint4 u; __half h[8]; };

__global__ __launch_bounds__(256) void fused_bh_transpose(const float* __restrict__ x,
                                                          const float* __restrict__ rays_o,
                                                          const float* __restrict__ scale,
                                                          unsigned* __restrict__ breaks,
                                                          unsigned* __restrict__ hist,
                                                          TransposeArgs a) {
  const int bid = blockIdx.x;
  if (bid < NB_BH) {
    // ---- break + histogram ----
    const unsigned t = (unsigned)bid * 256u + threadIdx.x;  // [0, NPTS)
    const float s0 = scale[0], s1 = scale[1], s2 = scale[2];
    const float xs0 = x[t * 3 + 0] * s0;
    const float xs1 = x[t * 3 + 1] * s1;
    const float xs2 = x[t * 3 + 2] * s2;
    const float dx = rays_o[0] - xs0;
    const float dy = rays_o[1] - xs1;
    const float dz = rays_o[2] - xs2;
    const float d = sqrtf(__fadd_rn(__fadd_rn(__fmul_rn(dx, dx), __fmul_rn(dy, dy)),
                                    __fmul_rn(dz, dz)));
    // inverted: max(NPTS - t) over candidates == min index; 0 = no candidate
    unsigned m1 = (d > 1.5f) ? (NPTS - t) : 0u;
    unsigned m2 = (d > 2.0f) ? (NPTS - t) : 0u;
#pragma unroll
    for (int o = 32; o > 0; o >>= 1) {
      m1 = max(m1, (unsigned)__shfl_down((int)m1, o, 64));
      m2 = max(m2, (unsigned)__shfl_down((int)m2, o, 64));
    }
    if ((threadIdx.x & 63) == 0) {
      atomicMax(&breaks[0], m1);
      atomicMax(&breaks[1], m2);
    }
    const unsigned key = cell_key(xs0, xs1, xs2);
    atomicAdd(&hist[key], 1u);
    return;
  }
  // ---- transpose: 9x [C][S][S] fp32 -> [S*S][C] fp16, no LDS ----
  const int tile = bid - NB_BH;
  int pi = 0;
#pragma unroll
  for (int i = 0; i < 9; ++i) {
    if (tile >= a.tile_hi[i]) pi = i + 1;
  }
  const int lo = (pi == 0) ? 0 : a.tile_hi[pi - 1];
  const float* __restrict__ src = a.src[pi];
  __half* __restrict__ dst = a.dst[pi];
  const size_t SS = (size_t)a.SS[pi];

  const int ntm = (int)(SS / TPIX) - 1;
  const int tl = ((tile - lo) * 997) & ntm;  // bijective tile scatter

  const int t = threadIdx.x;
  const int slot = t >> 3;  // 0..31
  const int c8 = t & 7;     // 0..7
  const size_t p0 = (size_t)tl * TPIX + (size_t)slot * 4;
  const float* __restrict__ srcb = src + (size_t)(c8 * 8) * SS + p0;

  H8 h[4];
#pragma unroll
  for (int k = 0; k < 8; ++k) {
    const float4 v = *(const float4*)(srcb + (size_t)k * SS);
    h[0].h[k] = __float2half(v.x);
    h[1].h[k] = __float2half(v.y);
    h[2].h[k] = __float2half(v.z);
    h[3].h[k] = __float2half(v.w);
  }
#pragma unroll
  for (int r = 0; r < 4; ++r) {
    *(uint4*)(dst + (p0 + (size_t)r) * FDIM + c8 * 8) = h[r].u;
  }
}

// ---------- single-block exclusive scan over NCELL=4096 entries ----------
__global__ __launch_bounds__(1024) void scan_kernel(unsigned* __restrict__ hist) {
  const int tid = threadIdx.x;  // 1 block x 1024, 4 cells/thread
  uint4 h = ((uint4*)hist)[tid];
  const unsigned i0 = h.x;
  const unsigned i1 = i0 + h.y;
  const unsigned i2 = i1 + h.z;
  const unsigned i3 = i2 + h.w;
  __shared__ unsigned ls[1024];
  ls[tid] = i3;
  __syncthreads();
  for (int d = 1; d < 1024; d <<= 1) {
    const unsigned add = (tid >= d) ? ls[tid - d] : 0u;
    __syncthreads();
    ls[tid] += add;
    __syncthreads();
  }
  const unsigned base = ls[tid] - i3;
  uint4 o;
  o.x = base;
  o.y = base + i0;
  o.z = base + i1;
  o.w = base + i2;
  ((uint4*)hist)[tid] = o;  // hist now holds global exclusive bases
}

// ---------- scatter: 4B records only (order | level<<18) ----------
// 1 MB of scattered 4B writes; L2 merges. (16B float4 records here cost
// +60 us in rounds 1-2: partial-line RFO ping-pong across XCDs.)
__global__ __launch_bounds__(256) void scatter_kernel(const float* __restrict__ x,
                                                      const float* __restrict__ scale,
                                                      const unsigned* __restrict__ breaks,
                                                      unsigned* __restrict__ offs,
                                                      unsigned* __restrict__ order) {
  const unsigned t = blockIdx.x * 256u + threadIdx.x;  // NPTS threads
  const float s0 = scale[0], s1 = scale[1], s2 = scale[2];
  const float xs0 = x[t * 3 + 0] * s0;
  const float xs1 = x[t * 3 + 1] * s1;
  const float xs2 = x[t * 3 + 2] * s2;
  const unsigned key = cell_key(xs0, xs1, xs2);
  const unsigned pos = atomicAdd(&offs[key], 1u);
  unsigned b1 = NPTS - breaks[0]; if (b1 >= NPTS) b1 = 0;  // raw=0 -> none -> 0
  unsigned b2 = NPTS - breaks[1]; if (b2 >= NPTS) b2 = 0;
  const unsigned lvl = (t < b1) ? 0u : ((t < b2) ? 1u : 2u);
  order[pos] = t | (lvl << 18);  // NPTS = 2^18
}

// ---------- bilinear sampling helpers ----------
__device__ __forceinline__ void bilinear_weights(int W, float cx, float cy,
                                                 float& w00, float& w01, float& w10, float& w11,
                                                 int& xc0, int& xc1, int& yc0, int& yc1) {
  const float Wm1 = (float)(W - 1);
  const float fx = (cx + 1.0f) * 0.5f * Wm1;
  const float fy = (cy + 1.0f) * 0.5f * Wm1;
  const float x0f = floorf(fx), y0f = floorf(fy);
  const float wx = fx - x0f, wy = fy - y0f;
  const int ix = (int)x0f, iy = (int)y0f;
  const int ix1 = ix + 1, iy1 = iy + 1;
  const bool vx0 = (ix >= 0) && (ix < W);
  const bool vx1 = (ix1 >= 0) && (ix1 < W);
  const bool vy0 = (iy >= 0) && (iy < W);
  const bool vy1 = (iy1 >= 0) && (iy1 < W);
  xc0 = min(max(ix, 0), W - 1);
  xc1 = min(max(ix1, 0), W - 1);
  yc0 = min(max(iy, 0), W - 1);
  yc1 = min(max(iy1, 0), W - 1);
  w00 = (1.0f - wx) * (1.0f - wy) * (float)(vx0 && vy0);
  w01 = wx * (1.0f - wy) * (float)(vx1 && vy0);
  w10 = (1.0f - wx) * wy * (float)(vx0 && vy1);
  w11 = wx * wy * (float)(vx1 && vy1);
}

__device__ __forceinline__ void sample8_t(const __half* __restrict__ pl, int W,
                                          float cx, float cy, int j8, float acc[8]) {
  float w00, w01, w10, w11;
  int xc0, xc1, yc0, yc1;
  bilinear_weights(W, cx, cy, w00, w01, w10, w11, xc0, xc1, yc0, yc1);
  const __half* b00 = pl + ((size_t)(yc0 * W + xc0) * FDIM + j8);
  const __half* b01 = pl + ((size_t)(yc0 * W + xc1) * FDIM + j8);
  const __half* b10 = pl + ((size_t)(yc1 * W + xc0) * FDIM + j8);
  const __half* b11 = pl + ((size_t)(yc1 * W + xc1) * FDIM + j8);
  H8 v00, v01, v10, v11;
  v00.u = *(const uint4*)b00;
  v01.u = *(const uint4*)b01;
  v10.u = *(const uint4*)b10;
  v11.u = *(const uint4*)b11;
#pragma unroll
  for (int k = 0; k < 8; ++k) {
    acc[k] += w00 * __half2float(v00.h[k]) + w01 * __half2float(v01.h[k]) +
              w10 * __half2float(v10.h[k]) + w11 * __half2float(v11.h[k]);
  }
}

__device__ __forceinline__ void sample8_d(const float* __restrict__ pl, int W,
                                          float cx, float cy, int j8, float acc[8]) {
  float w00, w01, w10, w11;
  int xc0, xc1, yc0, yc1;
  bilinear_weights(W, cx, cy, w00, w01, w10, w11, xc0, xc1, yc0, yc1);
  const size_t SS = (size_t)W * W;
  const int i00 = yc0 * W + xc0, i01 = yc0 * W + xc1;
  const int i10 = yc1 * W + xc0, i11 = yc1 * W + xc1;
#pragma unroll
  for (int k = 0; k < 8; ++k) {
    const size_t co = (size_t)(j8 + k) * SS;
    acc[k] += w00 * pl[co + i00] + w01 * pl[co + i01] +
              w10 * pl[co + i10] + w11 * pl[co + i11];
  }
}

struct PlanesH { const __half* p[9]; };
struct PlanesF { const float* p[9]; };

// ---------- main sampling kernel (fp16 transposed planes, sorted order) ----------
#define SAMPLE_BLOCKS (NPTS * 8 / 256)  // 8192
#define XCD_CHUNK (SAMPLE_BLOCKS / 8)   // 1024

__global__ __launch_bounds__(256) void sample_kernel(const float* __restrict__ x,
                                                     const float* __restrict__ scale,
                                                     const unsigned* __restrict__ order,
                                                     PlanesH tp, float* __restrict__ out) {
  const unsigned b = blockIdx.x;
  const unsigned sb = (b & 7u) * XCD_CHUNK + (b >> 3);  // XCD-aware bijective swizzle
  const int t = (int)(sb * 256u + threadIdx.x);
  const int slot = t >> 3;
  const int j8 = (t & 7) * 8;
  const unsigned pk = order[slot];  // 4B, broadcast across the point's 8 threads
  const int p = (int)(pk & 0x3FFFFu);
  const int level = (int)(pk >> 18);
  const float s0 = scale[0], s1 = scale[1], s2 = scale[2];
  const float xs0 = x[p * 3 + 0] * s0;  // 3 MB region, L2/L3-resident
  const float xs1 = x[p * 3 + 1] * s1;
  const float xs2 = x[p * 3 + 2] * s2;
  float acc[8];
#pragma unroll
  for (int k = 0; k < 8; ++k) acc[k] = 0.0f;
  sample8_t(tp.p[0], 512, xs0, xs1, j8, acc);  // xy: (x,y)
  sample8_t(tp.p[1], 512, xs1, xs2, j8, acc);  // yz: (y,z)
  sample8_t(tp.p[2], 512, xs0, xs2, j8, acc);  // xz: (x,z)
  if (level >= 1) {
    sample8_t(tp.p[3], 256, xs0, xs1, j8, acc);
    sample8_t(tp.p[4], 256, xs1, xs2, j8, acc);
    sample8_t(tp.p[5], 256, xs0, xs2, j8, acc);
  }
  if (level >= 2) {
    sample8_t(tp.p[6], 128, xs0, xs1, j8, acc);
    sample8_t(tp.p[7], 128, xs1, xs2, j8, acc);
    sample8_t(tp.p[8], 128, xs0, xs2, j8, acc);
  }
  float* o = out + (size_t)p * FDIM + j8;
  vfloat4 lo = {acc[0], acc[1], acc[2], acc[3]};
  vfloat4 hi = {acc[4], acc[5], acc[6], acc[7]};
  __builtin_nontemporal_store(lo, (vfloat4*)o);
  __builtin_nontemporal_store(hi, (vfloat4*)(o + 4));
}

// ---------- fallback: sample directly from fp32 [C][H][W], unsorted ----------
__global__ __launch_bounds__(256) void sample_kernel_direct(const float* __restrict__ x,
                                                            const float* __restrict__ scale,
                                                            const unsigned* __restrict__ breaks,
                                                            PlanesF tp, float* __restrict__ out) {
  const int t = blockIdx.x * 256 + threadIdx.x;
  const int p = t >> 3;
  const int j8 = (t & 7) * 8;
  const float s0 = scale[0], s1 = scale[1], s2 = scale[2];
  const float xs0 = x[p * 3 + 0] * s0;
  const float xs1 = x[p * 3 + 1] * s1;
  const float xs2 = x[p * 3 + 2] * s2;
  unsigned b1 = breaks[0]; if (b1 >= NPTS) b1 = 0;
  unsigned b2 = breaks[1]; if (b2 >= NPTS) b2 = 0;
  const unsigned pu = (unsigned)p;
  const int level = (pu < b1) ? 0 : ((pu < b2) ? 1 : 2);
  float acc[8];
#pragma unroll
  for (int k = 0; k < 8; ++k) acc[k] = 0.0f;
  sample8_d(tp.p[0], 512, xs0, xs1, j8, acc);
  sample8_d(tp.p[1], 512, xs1, xs2, j8, acc);
  sample8_d(tp.p[2], 512, xs0, xs2, j8, acc);
  if (level >= 1) {
    sample8_d(tp.p[3], 256, xs0, xs1, j8, acc);
    sample8_d(tp.p[4], 256, xs1, xs2, j8, acc);
    sample8_d(tp.p[5], 256, xs0, xs2, j8, acc);
  }
  if (level >= 2) {
    sample8_d(tp.p[6], 128, xs0, xs1, j8, acc);
    sample8_d(tp.p[7], 128, xs1, xs2, j8, acc);
    sample8_d(tp.p[8], 128, xs0, xs2, j8, acc);
  }
  float4* o4 = (float4*)(out + (size_t)p * FDIM + j8);
  o4[0] = make_float4(acc[0], acc[1], acc[2], acc[3]);
  o4[1] = make_float4(acc[4], acc[5], acc[6], acc[7]);
}

extern "C" void kernel_launch(void* const* d_in, const int* in_sizes, int n_in,
                              void* d_out, int out_size, void* d_ws, size_t ws_size,
                              hipStream_t stream) {
  const float* x = (const float*)d_in[0];
  const float* rays_o = (const float*)d_in[1];
  const float* scale = (const float*)d_in[2];
  const float* pl32[9];
  for (int i = 0; i < 9; ++i) pl32[i] = (const float*)d_in[3 + i];
  float* out = (float*)d_out;

  unsigned char* ws = (unsigned char*)d_ws;
  // ws layout: breaks @0 (8B, 0-init) | hist @256 (16 KB, 0-init) |
  //            order @16640 (1 MB) | planes @1065216
  unsigned* breaks = (unsigned*)ws;
  unsigned* hist = (unsigned*)(ws + 256);
  unsigned* order = (unsigned*)(ws + 256 + NCELL * 4);
  const size_t planes_off = 256 + (size_t)NCELL * 4 + (size_t)NPTS * 4;

  const int Ss[3] = {512, 256, 128};
  size_t need = planes_off;
  for (int l = 0; l < 3; ++l) need += 3 * (size_t)Ss[l] * Ss[l] * FDIM * sizeof(__half);

  if (ws_size >= need) {
    (void)hipMemsetAsync(d_ws, 0, 256 + NCELL * 4, stream);  // breaks + hist

    PlanesH tp;
    TransposeArgs ta;
    size_t off = planes_off;
    int tiles_acc = 0;
    for (int l = 0; l < 3; ++l) {
      const int S = Ss[l];
      const int SS = S * S;
      for (int o = 0; o < 3; ++o) {
        const int i = l * 3 + o;
        __half* dst = (__half*)(ws + off);
        tp.p[i] = dst;
        ta.src[i] = pl32[i];
        ta.dst[i] = dst;
        ta.SS[i] = SS;
        tiles_acc += SS / TPIX;
        ta.tile_hi[i] = tiles_acc;
        off += (size_t)SS * FDIM * sizeof(__half);
      }
    }
    fused_bh_transpose<<<NB_BH + tiles_acc, 256, 0, stream>>>(x, rays_o, scale,
                                                              breaks, hist, ta);
    scan_kernel<<<1, 1024, 0, stream>>>(hist);
    scatter_kernel<<<NPTS / 256, 256, 0, stream>>>(x, scale, breaks, hist, order);
    sample_kernel<<<SAMPLE_BLOCKS, 256, 0, stream>>>(x, scale, order, tp, out);
  } else {
    (void)hipMemsetAsync(d_ws, 0xFF, 8, stream);  // sentinel for atomicMin path
    break_kernel<<<256, 256, 0, stream>>>(x, rays_o, scale, breaks);
    PlanesF tf;
    for (int i = 0; i < 9; ++i) tf.p[i] = pl32[i];
    sample_kernel_direct<<<(NPTS * 8) / 256, 256, 0, stream>>>(x, scale, breaks, tf, out);
  }
}

// Round 4
// 426.446 us; speedup vs baseline: 1.1500x; 1.1137x over previous
//
#include <hip/hip_runtime.h>
#include <hip/hip_fp16.h>

#define NPTS 262144
#define FDIM 64
#define NCELL 4096   // 16^3 Morton cells, avg 64 pts/cell
#define NBLK 64      // sort blocks
#define PPT 16       // points per thread in sort kernels (64*256*16 = NPTS)

typedef float vfloat4 __attribute__((ext_vector_type(4)));

// ---------- standalone break kernel (fallback path only) ----------
__global__ __launch_bounds__(256) void break_kernel(const float* __restrict__ x,
                                                    const float* __restrict__ rays_o,
                                                    const float* __restrict__ scale,
                                                    unsigned* __restrict__ breaks) {
  const unsigned t = blockIdx.x * 256u + threadIdx.x;
  const float r0 = rays_o[0], r1 = rays_o[1], r2 = rays_o[2];
  const float s0 = scale[0], s1 = scale[1], s2 = scale[2];
  unsigned b1 = 0xFFFFFFFFu, b2 = 0xFFFFFFFFu;
  for (unsigned p = t; p < NPTS; p += 65536u) {
    const float dx = r0 - x[p * 3 + 0] * s0;
    const float dy = r1 - x[p * 3 + 1] * s1;
    const float dz = r2 - x[p * 3 + 2] * s2;
    const float d = sqrtf(__fadd_rn(__fadd_rn(__fmul_rn(dx, dx), __fmul_rn(dy, dy)),
                                    __fmul_rn(dz, dz)));
    if (d > 1.5f) b1 = min(b1, p);
    if (d > 2.0f) b2 = min(b2, p);
  }
#pragma unroll
  for (int o = 32; o > 0; o >>= 1) {
    b1 = min(b1, (unsigned)__shfl_down((int)b1, o, 64));
    b2 = min(b2, (unsigned)__shfl_down((int)b2, o, 64));
  }
  if ((threadIdx.x & 63) == 0) {
    atomicMin(&breaks[0], b1);
    atomicMin(&breaks[1], b2);
  }
}

// ---------- Morton cell key (16^3) ----------
__device__ __forceinline__ unsigned part4(unsigned v) {
  v &= 15u;
  v = (v | (v << 4)) & 0x0C3u;
  v = (v | (v << 2)) & 0x249u;
  return v;
}

__device__ __forceinline__ unsigned cell_key(float x0, float x1, float x2) {
  const int cx = min(max((int)((x0 + 1.0f) * 8.0f), 0), 15);
  const int cy = min(max((int)((x1 + 1.0f) * 8.0f), 0), 15);
  const int cz = min(max((int)((x2 + 1.0f) * 8.0f), 0), 15);
  return part4((unsigned)cx) | (part4((unsigned)cy) << 1) | (part4((unsigned)cz) << 2);
}

// ---------- k1: breaks + LDS-private histogram + key cache ----------
// Global atomics in the whole sort: 128 atomicMax to 2 words (trivial).
// Prior design's 256K global atomicAdds cost ~100 us each in hist AND
// scatter (each showed as ~32B memory-side RMW in WRITE_SIZE).
__global__ __launch_bounds__(256) void bh_hist_kernel(const float* __restrict__ x,
                                                      const float* __restrict__ rays_o,
                                                      const float* __restrict__ scale,
                                                      unsigned* __restrict__ breaks,
                                                      unsigned short* __restrict__ keys,
                                                      unsigned* __restrict__ blockhist) {
  __shared__ unsigned lh[NCELL];
  for (int i = threadIdx.x; i < NCELL; i += 256) lh[i] = 0u;
  __syncthreads();
  const float r0 = rays_o[0], r1 = rays_o[1], r2 = rays_o[2];
  const float s0 = scale[0], s1 = scale[1], s2 = scale[2];
  const unsigned base = blockIdx.x * 256u + threadIdx.x;
  unsigned m1 = 0u, m2 = 0u;
#pragma unroll
  for (int k = 0; k < PPT; ++k) {
    const unsigned p = base + (unsigned)k * (NBLK * 256u);
    const float xs0 = x[p * 3 + 0] * s0;
    const float xs1 = x[p * 3 + 1] * s1;
    const float xs2 = x[p * 3 + 2] * s2;
    const float dx = r0 - xs0;
    const float dy = r1 - xs1;
    const float dz = r2 - xs2;
    const float d = sqrtf(__fadd_rn(__fadd_rn(__fmul_rn(dx, dx), __fmul_rn(dy, dy)),
                                    __fmul_rn(dz, dz)));
    // inverted: max(NPTS - p) over candidates == min index; 0 = no candidate
    if (d > 1.5f) m1 = max(m1, NPTS - p);
    if (d > 2.0f) m2 = max(m2, NPTS - p);
    const unsigned key = cell_key(xs0, xs1, xs2);
    atomicAdd(&lh[key], 1u);  // LDS atomic: CU-local, cheap
    keys[p] = (unsigned short)key;
  }
#pragma unroll
  for (int o = 32; o > 0; o >>= 1) {
    m1 = max(m1, (unsigned)__shfl_down((int)m1, o, 64));
    m2 = max(m2, (unsigned)__shfl_down((int)m2, o, 64));
  }
  if ((threadIdx.x & 63) == 0) {
    atomicMax(&breaks[0], m1);
    atomicMax(&breaks[1], m2);
  }
  __syncthreads();
  unsigned* bh = blockhist + (size_t)blockIdx.x * NCELL;
  for (int i = threadIdx.x; i < NCELL; i += 256) bh[i] = lh[i];  // plain coalesced
}

// ---------- k2: turn blockhist counts into global start offsets ----------
// 1 block x 1024 threads, each owns 4 cells (uint4). Pass 1: per-cell totals.
// LDS scan -> global cell bases. Pass 2: rewrite blockhist[b][c] in place as
// the running base for (block b, cell c). ~3 MB, L2-hot.
__global__ __launch_bounds__(1024) void scan_kernel(unsigned* __restrict__ blockhist) {
  const int tid = threadIdx.x;
  uint4 acc = make_uint4(0u, 0u, 0u, 0u);
  for (int b = 0; b < NBLK; ++b) {
    const uint4 v = ((const uint4*)(blockhist + (size_t)b * NCELL))[tid];
    acc.x += v.x; acc.y += v.y; acc.z += v.z; acc.w += v.w;
  }
  const unsigned i0 = acc.x;
  const unsigned i1 = i0 + acc.y;
  const unsigned i2 = i1 + acc.z;
  const unsigned i3 = i2 + acc.w;
  __shared__ unsigned ls[1024];
  ls[tid] = i3;
  __syncthreads();
  for (int d = 1; d < 1024; d <<= 1) {
    const unsigned add = (tid >= d) ? ls[tid - d] : 0u;
    __syncthreads();
    ls[tid] += add;
    __syncthreads();
  }
  const unsigned base = ls[tid] - i3;  // exclusive prefix of this thread's 4 cells
  uint4 run;
  run.x = base;
  run.y = base + i0;
  run.z = base + i1;
  run.w = base + i2;
  for (int b = 0; b < NBLK; ++b) {
    uint4* ptr = (uint4*)(blockhist + (size_t)b * NCELL) + tid;
    const uint4 v = *ptr;
    *ptr = run;
    run.x += v.x; run.y += v.y; run.z += v.z; run.w += v.w;
  }
}

// ---------- k3: scatter via LDS base row (atomic-free in global) ----------
__global__ __launch_bounds__(256) void scatter_kernel(const unsigned short* __restrict__ keys,
                                                      const unsigned* __restrict__ breaks,
                                                      const unsigned* __restrict__ blockhist,
                                                      unsigned* __restrict__ order) {
  __shared__ unsigned lh[NCELL];
  const unsigned* bh = blockhist + (size_t)blockIdx.x * NCELL;
  for (int i = threadIdx.x; i < NCELL; i += 256) lh[i] = bh[i];
  __syncthreads();
  unsigned b1 = NPTS - breaks[0]; if (b1 >= NPTS) b1 = 0u;  // raw=0 -> none -> 0
  unsigned b2 = NPTS - breaks[1]; if (b2 >= NPTS) b2 = 0u;
  const unsigned base = blockIdx.x * 256u + threadIdx.x;
#pragma unroll
  for (int k = 0; k < PPT; ++k) {
    const unsigned p = base + (unsigned)k * (NBLK * 256u);
    const unsigned key = keys[p];
    const unsigned pos = atomicAdd(&lh[key], 1u);  // LDS atomic -> exact global slot
    const unsigned lvl = (p < b1) ? 0u : ((p < b2) ? 1u : 2u);
    order[pos] = p | (lvl << 18);  // NPTS = 2^18
  }
}

// ---------- transpose: 9x [C][S][S] fp32 -> [S*S][C] fp16, no LDS ----------
#define TPIX 128  // pixels per block

struct TransposeArgs {
  const float* src[9];
  __half* dst[9];
  int tile_hi[9];  // inclusive prefix sum of tiles per plane
  int SS[9];
};

union H8 { uint4 u; __half h[8]; };

__global__ __launch_bounds__(256) void transpose_all(TransposeArgs a) {
  const int tile = blockIdx.x;
  int pi = 0;
#pragma unroll
  for (int i = 0; i < 9; ++i) {
    if (tile >= a.tile_hi[i]) pi = i + 1;
  }
  const int lo = (pi == 0) ? 0 : a.tile_hi[pi - 1];
  const float* __restrict__ src = a.src[pi];
  __half* __restrict__ dst = a.dst[pi];
  const size_t SS = (size_t)a.SS[pi];

  const int ntm = (int)(SS / TPIX) - 1;
  const int tl = ((tile - lo) * 997) & ntm;  // bijective tile scatter

  const int t = threadIdx.x;
  const int slot = t >> 3;  // 0..31
  const int c8 = t & 7;     // 0..7
  const size_t p0 = (size_t)tl * TPIX + (size_t)slot * 4;
  const float* __restrict__ srcb = src + (size_t)(c8 * 8) * SS + p0;

  H8 h[4];
#pragma unroll
  for (int k = 0; k < 8; ++k) {
    const float4 v = *(const float4*)(srcb + (size_t)k * SS);
    h[0].h[k] = __float2half(v.x);
    h[1].h[k] = __float2half(v.y);
    h[2].h[k] = __float2half(v.z);
    h[3].h[k] = __float2half(v.w);
  }
#pragma unroll
  for (int r = 0; r < 4; ++r) {
    *(uint4*)(dst + (p0 + (size_t)r) * FDIM + c8 * 8) = h[r].u;
  }
}

// ---------- bilinear sampling helpers ----------
__device__ __forceinline__ void bilinear_weights(int W, float cx, float cy,
                                                 float& w00, float& w01, float& w10, float& w11,
                                                 int& xc0, int& xc1, int& yc0, int& yc1) {
  const float Wm1 = (float)(W - 1);
  const float fx = (cx + 1.0f) * 0.5f * Wm1;
  const float fy = (cy + 1.0f) * 0.5f * Wm1;
  const float x0f = floorf(fx), y0f = floorf(fy);
  const float wx = fx - x0f, wy = fy - y0f;
  const int ix = (int)x0f, iy = (int)y0f;
  const int ix1 = ix + 1, iy1 = iy + 1;
  const bool vx0 = (ix >= 0) && (ix < W);
  const bool vx1 = (ix1 >= 0) && (ix1 < W);
  const bool vy0 = (iy >= 0) && (iy < W);
  const bool vy1 = (iy1 >= 0) && (iy1 < W);
  xc0 = min(max(ix, 0), W - 1);
  xc1 = min(max(ix1, 0), W - 1);
  yc0 = min(max(iy, 0), W - 1);
  yc1 = min(max(iy1, 0), W - 1);
  w00 = (1.0f - wx) * (1.0f - wy) * (float)(vx0 && vy0);
  w01 = wx * (1.0f - wy) * (float)(vx1 && vy0);
  w10 = (1.0f - wx) * wy * (float)(vx0 && vy1);
  w11 = wx * wy * (float)(vx1 && vy1);
}

__device__ __forceinline__ void sample8_t(const __half* __restrict__ pl, int W,
                                          float cx, float cy, int j8, float acc[8]) {
  float w00, w01, w10, w11;
  int xc0, xc1, yc0, yc1;
  bilinear_weights(W, cx, cy, w00, w01, w10, w11, xc0, xc1, yc0, yc1);
  const __half* b00 = pl + ((size_t)(yc0 * W + xc0) * FDIM + j8);
  const __half* b01 = pl + ((size_t)(yc0 * W + xc1) * FDIM + j8);
  const __half* b10 = pl + ((size_t)(yc1 * W + xc0) * FDIM + j8);
  const __half* b11 = pl + ((size_t)(yc1 * W + xc1) * FDIM + j8);
  H8 v00, v01, v10, v11;
  v00.u = *(const uint4*)b00;
  v01.u = *(const uint4*)b01;
  v10.u = *(const uint4*)b10;
  v11.u = *(const uint4*)b11;
#pragma unroll
  for (int k = 0; k < 8; ++k) {
    acc[k] += w00 * __half2float(v00.h[k]) + w01 * __half2float(v01.h[k]) +
              w10 * __half2float(v10.h[k]) + w11 * __half2float(v11.h[k]);
  }
}

__device__ __forceinline__ void sample8_d(const float* __restrict__ pl, int W,
                                          float cx, float cy, int j8, float acc[8]) {
  float w00, w01, w10, w11;
  int xc0, xc1, yc0, yc1;
  bilinear_weights(W, cx, cy, w00, w01, w10, w11, xc0, xc1, yc0, yc1);
  const size_t SS = (size_t)W * W;
  const int i00 = yc0 * W + xc0, i01 = yc0 * W + xc1;
  const int i10 = yc1 * W + xc0, i11 = yc1 * W + xc1;
#pragma unroll
  for (int k = 0; k < 8; ++k) {
    const size_t co = (size_t)(j8 + k) * SS;
    acc[k] += w00 * pl[co + i00] + w01 * pl[co + i01] +
              w10 * pl[co + i10] + w11 * pl[co + i11];
  }
}

struct PlanesH { const __half* p[9]; };
struct PlanesF { const float* p[9]; };

// ---------- main sampling kernel (fp16 transposed planes, sorted order) ----------
#define SAMPLE_BLOCKS (NPTS * 8 / 256)  // 8192
#define XCD_CHUNK (SAMPLE_BLOCKS / 8)   // 1024

__global__ __launch_bounds__(256) void sample_kernel(const float* __restrict__ x,
                                                     const float* __restrict__ scale,
                                                     const unsigned* __restrict__ order,
                                                     PlanesH tp, float* __restrict__ out) {
  const unsigned b = blockIdx.x;
  const unsigned sb = (b & 7u) * XCD_CHUNK + (b >> 3);  // XCD-aware bijective swizzle
  const int t = (int)(sb * 256u + threadIdx.x);
  const int slot = t >> 3;
  const int j8 = (t & 7) * 8;
  const unsigned pk = order[slot];  // 4B, broadcast across the point's 8 threads
  const int p = (int)(pk & 0x3FFFFu);
  const int level = (int)(pk >> 18);
  const float s0 = scale[0], s1 = scale[1], s2 = scale[2];
  const float xs0 = x[p * 3 + 0] * s0;  // 3 MB region, cache-resident
  const float xs1 = x[p * 3 + 1] * s1;
  const float xs2 = x[p * 3 + 2] * s2;
  float acc[8];
#pragma unroll
  for (int k = 0; k < 8; ++k) acc[k] = 0.0f;
  sample8_t(tp.p[0], 512, xs0, xs1, j8, acc);  // xy: (x,y)
  sample8_t(tp.p[1], 512, xs1, xs2, j8, acc);  // yz: (y,z)
  sample8_t(tp.p[2], 512, xs0, xs2, j8, acc);  // xz: (x,z)
  if (level >= 1) {
    sample8_t(tp.p[3], 256, xs0, xs1, j8, acc);
    sample8_t(tp.p[4], 256, xs1, xs2, j8, acc);
    sample8_t(tp.p[5], 256, xs0, xs2, j8, acc);
  }
  if (level >= 2) {
    sample8_t(tp.p[6], 128, xs0, xs1, j8, acc);
    sample8_t(tp.p[7], 128, xs1, xs2, j8, acc);
    sample8_t(tp.p[8], 128, xs0, xs2, j8, acc);
  }
  float* o = out + (size_t)p * FDIM + j8;
  vfloat4 lo = {acc[0], acc[1], acc[2], acc[3]};
  vfloat4 hi = {acc[4], acc[5], acc[6], acc[7]};
  __builtin_nontemporal_store(lo, (vfloat4*)o);
  __builtin_nontemporal_store(hi, (vfloat4*)(o + 4));
}

// ---------- fallback: sample directly from fp32 [C][H][W], unsorted ----------
__global__ __launch_bounds__(256) void sample_kernel_direct(const float* __restrict__ x,
                                                            const float* __restrict__ scale,
                                                            const unsigned* __restrict__ breaks,
                                                            PlanesF tp, float* __restrict__ out) {
  const int t = blockIdx.x * 256 + threadIdx.x;
  const int p = t >> 3;
  const int j8 = (t & 7) * 8;
  const float s0 = scale[0], s1 = scale[1], s2 = scale[2];
  const float xs0 = x[p * 3 + 0] * s0;
  const float xs1 = x[p * 3 + 1] * s1;
  const float xs2 = x[p * 3 + 2] * s2;
  unsigned b1 = breaks[0]; if (b1 >= NPTS) b1 = 0;
  unsigned b2 = breaks[1]; if (b2 >= NPTS) b2 = 0;
  const unsigned pu = (unsigned)p;
  const int level = (pu < b1) ? 0 : ((pu < b2) ? 1 : 2);
  float acc[8];
#pragma unroll
  for (int k = 0; k < 8; ++k) acc[k] = 0.0f;
  sample8_d(tp.p[0], 512, xs0, xs1, j8, acc);
  sample8_d(tp.p[1], 512, xs1, xs2, j8, acc);
  sample8_d(tp.p[2], 512, xs0, xs2, j8, acc);
  if (level >= 1) {
    sample8_d(tp.p[3], 256, xs0, xs1, j8, acc);
    sample8_d(tp.p[4], 256, xs1, xs2, j8, acc);
    sample8_d(tp.p[5], 256, xs0, xs2, j8, acc);
  }
  if (level >= 2) {
    sample8_d(tp.p[6], 128, xs0, xs1, j8, acc);
    sample8_d(tp.p[7], 128, xs1, xs2, j8, acc);
    sample8_d(tp.p[8], 128, xs0, xs2, j8, acc);
  }
  float4* o4 = (float4*)(out + (size_t)p * FDIM + j8);
  o4[0] = make_float4(acc[0], acc[1], acc[2], acc[3]);
  o4[1] = make_float4(acc[4], acc[5], acc[6], acc[7]);
}

extern "C" void kernel_launch(void* const* d_in, const int* in_sizes, int n_in,
                              void* d_out, int out_size, void* d_ws, size_t ws_size,
                              hipStream_t stream) {
  const float* x = (const float*)d_in[0];
  const float* rays_o = (const float*)d_in[1];
  const float* scale = (const float*)d_in[2];
  const float* pl32[9];
  for (int i = 0; i < 9; ++i) pl32[i] = (const float*)d_in[3 + i];
  float* out = (float*)d_out;

  unsigned char* ws = (unsigned char*)d_ws;
  // ws layout: breaks @0 (8B, 0-init) | keys @256 (512 KB) |
  //            blockhist @524544 (1 MB) | order @1573120 (1 MB) | planes @2621696
  unsigned* breaks = (unsigned*)ws;
  unsigned short* keys = (unsigned short*)(ws + 256);
  unsigned* blockhist = (unsigned*)(ws + 256 + (size_t)NPTS * 2);
  unsigned* order = (unsigned*)(ws + 256 + (size_t)NPTS * 2 + (size_t)NBLK * NCELL * 4);
  const size_t planes_off = 256 + (size_t)NPTS * 2 + (size_t)NBLK * NCELL * 4 + (size_t)NPTS * 4;

  const int Ss[3] = {512, 256, 128};
  size_t need = planes_off;
  for (int l = 0; l < 3; ++l) need += 3 * (size_t)Ss[l] * Ss[l] * FDIM * sizeof(__half);

  if (ws_size >= need) {
    (void)hipMemsetAsync(d_ws, 0, 256, stream);  // breaks only

    bh_hist_kernel<<<NBLK, 256, 0, stream>>>(x, rays_o, scale, breaks, keys, blockhist);
    scan_kernel<<<1, 1024, 0, stream>>>(blockhist);
    scatter_kernel<<<NBLK, 256, 0, stream>>>(keys, breaks, blockhist, order);

    PlanesH tp;
    TransposeArgs ta;
    size_t off = planes_off;
    int tiles_acc = 0;
    for (int l = 0; l < 3; ++l) {
      const int S = Ss[l];
      const int SS = S * S;
      for (int o = 0; o < 3; ++o) {
        const int i = l * 3 + o;
        __half* dst = (__half*)(ws + off);
        tp.p[i] = dst;
        ta.src[i] = pl32[i];
        ta.dst[i] = dst;
        ta.SS[i] = SS;
        tiles_acc += SS / TPIX;
        ta.tile_hi[i] = tiles_acc;
        off += (size_t)SS * FDIM * sizeof(__half);
      }
    }
    transpose_all<<<tiles_acc, 256, 0, stream>>>(ta);
    sample_kernel<<<SAMPLE_BLOCKS, 256, 0, stream>>>(x, scale, order, tp, out);
  } else {
    (void)hipMemsetAsync(d_ws, 0xFF, 8, stream);  // sentinel for atomicMin path
    break_kernel<<<256, 256, 0, stream>>>(x, rays_o, scale, breaks);
    PlanesF tf;
    for (int i = 0; i < 9; ++i) tf.p[i] = pl32[i];
    sample_kernel_direct<<<(NPTS * 8) / 256, 256, 0, stream>>>(x, scale, breaks, tf, out);
  }
}

// Round 5
// 413.311 us; speedup vs baseline: 1.1865x; 1.0318x over previous
//
#include <hip/hip_runtime.h>
#include <hip/hip_fp16.h>

#define NPTS 262144
#define FDIM 64
#define NCELL 4096   // 16^3 Morton cells, avg 64 pts/cell
#define NBLK 64      // sort blocks
#define PPT 16       // points per thread in sort kernels (64*256*16 = NPTS)

typedef float vfloat4 __attribute__((ext_vector_type(4)));

// ---------- standalone break kernel (fallback path only) ----------
__global__ __launch_bounds__(256) void break_kernel(const float* __restrict__ x,
                                                    const float* __restrict__ rays_o,
                                                    const float* __restrict__ scale,
                                                    unsigned* __restrict__ breaks) {
  const unsigned t = blockIdx.x * 256u + threadIdx.x;
  const float r0 = rays_o[0], r1 = rays_o[1], r2 = rays_o[2];
  const float s0 = scale[0], s1 = scale[1], s2 = scale[2];
  unsigned b1 = 0xFFFFFFFFu, b2 = 0xFFFFFFFFu;
  for (unsigned p = t; p < NPTS; p += 65536u) {
    const float dx = r0 - x[p * 3 + 0] * s0;
    const float dy = r1 - x[p * 3 + 1] * s1;
    const float dz = r2 - x[p * 3 + 2] * s2;
    const float d = sqrtf(__fadd_rn(__fadd_rn(__fmul_rn(dx, dx), __fmul_rn(dy, dy)),
                                    __fmul_rn(dz, dz)));
    if (d > 1.5f) b1 = min(b1, p);
    if (d > 2.0f) b2 = min(b2, p);
  }
#pragma unroll
  for (int o = 32; o > 0; o >>= 1) {
    b1 = min(b1, (unsigned)__shfl_down((int)b1, o, 64));
    b2 = min(b2, (unsigned)__shfl_down((int)b2, o, 64));
  }
  if ((threadIdx.x & 63) == 0) {
    atomicMin(&breaks[0], b1);
    atomicMin(&breaks[1], b2);
  }
}

// ---------- Morton cell key (16^3) ----------
__device__ __forceinline__ unsigned part4(unsigned v) {
  v &= 15u;
  v = (v | (v << 4)) & 0x0C3u;
  v = (v | (v << 2)) & 0x249u;
  return v;
}

__device__ __forceinline__ unsigned cell_key(float x0, float x1, float x2) {
  const int cx = min(max((int)((x0 + 1.0f) * 8.0f), 0), 15);
  const int cy = min(max((int)((x1 + 1.0f) * 8.0f), 0), 15);
  const int cz = min(max((int)((x2 + 1.0f) * 8.0f), 0), 15);
  return part4((unsigned)cx) | (part4((unsigned)cy) << 1) | (part4((unsigned)cz) << 2);
}

// ---------- fused dispatch: [0,NBLK) = break+hist blocks, rest = transpose ----------
// bh blocks (LDS-private hist, ~10 us on 64 CUs) ride along with the
// BW-bound transpose. Round-3's fusion failed because its hist used global
// atomics (~85 us serialized ahead of transpose); LDS hist is cheap.
//
// Transpose: TPIX=1024 -> each block covers a 4 KB contiguous run PER
// channel (8 sub-tiles of 512 B processed sequentially). Theory: the
// pattern-insensitive ~2.4 TB/s wall is address-translation / DRAM-page
// amortization at 512 B/stream granularity; 4 KB runs cut TLB walks and
// row-activates 8x. Per-instruction coalescing is unchanged.
#define TPIX 1024  // pixels per transpose block
#define SUBT 8     // 8 sub-tiles of 128 px

struct TransposeArgs {
  const float* src[9];
  __half* dst[9];
  int tile_hi[9];  // inclusive prefix sum of tiles per plane
  int SS[9];
};

union H8 { uint4 u; __half h[8]; };

__global__ __launch_bounds__(256) void fused_bh_transpose(const float* __restrict__ x,
                                                          const float* __restrict__ rays_o,
                                                          const float* __restrict__ scale,
                                                          unsigned* __restrict__ breaks,
                                                          unsigned short* __restrict__ keys,
                                                          unsigned* __restrict__ blockhist,
                                                          TransposeArgs a) {
  __shared__ unsigned lh[NCELL];  // used by bh blocks only (16 KB; no occ cost)
  const int bid = blockIdx.x;
  if (bid < NBLK) {
    // ---- break + LDS-private histogram + key cache ----
    for (int i = threadIdx.x; i < NCELL; i += 256) lh[i] = 0u;
    __syncthreads();
    const float r0 = rays_o[0], r1 = rays_o[1], r2 = rays_o[2];
    const float s0 = scale[0], s1 = scale[1], s2 = scale[2];
    const unsigned base = (unsigned)bid * 256u + threadIdx.x;
    unsigned m1 = 0u, m2 = 0u;
#pragma unroll
    for (int k = 0; k < PPT; ++k) {
      const unsigned p = base + (unsigned)k * (NBLK * 256u);
      const float xs0 = x[p * 3 + 0] * s0;
      const float xs1 = x[p * 3 + 1] * s1;
      const float xs2 = x[p * 3 + 2] * s2;
      const float dx = r0 - xs0;
      const float dy = r1 - xs1;
      const float dz = r2 - xs2;
      const float d = sqrtf(__fadd_rn(__fadd_rn(__fmul_rn(dx, dx), __fmul_rn(dy, dy)),
                                      __fmul_rn(dz, dz)));
      // inverted: max(NPTS - p) over candidates == min index; 0 = no candidate
      if (d > 1.5f) m1 = max(m1, NPTS - p);
      if (d > 2.0f) m2 = max(m2, NPTS - p);
      const unsigned key = cell_key(xs0, xs1, xs2);
      atomicAdd(&lh[key], 1u);  // LDS atomic: CU-local, cheap
      keys[p] = (unsigned short)key;
    }
#pragma unroll
    for (int o = 32; o > 0; o >>= 1) {
      m1 = max(m1, (unsigned)__shfl_down((int)m1, o, 64));
      m2 = max(m2, (unsigned)__shfl_down((int)m2, o, 64));
    }
    if ((threadIdx.x & 63) == 0) {
      atomicMax(&breaks[0], m1);
      atomicMax(&breaks[1], m2);
    }
    __syncthreads();
    unsigned* bh = blockhist + (size_t)bid * NCELL;
    for (int i = threadIdx.x; i < NCELL; i += 256) bh[i] = lh[i];  // plain coalesced
    return;
  }
  // ---- transpose: 9x [C][S][S] fp32 -> [S*S][C] fp16, no LDS ----
  const int tile = bid - NBLK;
  int pi = 0;
#pragma unroll
  for (int i = 0; i < 9; ++i) {
    if (tile >= a.tile_hi[i]) pi = i + 1;
  }
  const int lo = (pi == 0) ? 0 : a.tile_hi[pi - 1];
  const float* __restrict__ src = a.src[pi];
  __half* __restrict__ dst = a.dst[pi];
  const size_t SS = (size_t)a.SS[pi];

  const int ntm = (int)(SS / TPIX) - 1;
  const int tl = ((tile - lo) * 997) & ntm;  // bijective tile scatter

  const int t = threadIdx.x;
  const int slot = t >> 3;  // 0..31
  const int c8 = t & 7;     // 0..7
  const size_t tb = (size_t)tl * TPIX;
  const float* __restrict__ srcc = src + (size_t)(c8 * 8) * SS;

#pragma unroll
  for (int gi = 0; gi < SUBT; ++gi) {
    const size_t p0 = tb + (size_t)gi * 128 + (size_t)slot * 4;
    const float* __restrict__ srcb = srcc + p0;
    H8 h[4];
#pragma unroll
    for (int k = 0; k < 8; ++k) {
      const float4 v = *(const float4*)(srcb + (size_t)k * SS);
      h[0].h[k] = __float2half(v.x);
      h[1].h[k] = __float2half(v.y);
      h[2].h[k] = __float2half(v.z);
      h[3].h[k] = __float2half(v.w);
    }
#pragma unroll
    for (int r = 0; r < 4; ++r) {
      *(uint4*)(dst + (p0 + (size_t)r) * FDIM + c8 * 8) = h[r].u;
    }
  }
}

// ---------- scatter with inline redundant scan (replaces scan + scatter) ----------
// Each block re-derives the global base row for (block b, cell c):
//   cellbase[c] = exscan_c( sum_b hist[b][c] ),  base = cellbase + sum_{b'<b} hist[b'][c]
// by reading the full 1 MB blockhist (L2/L3-hot, ~10 us) + an LDS scan.
// Saves a dispatch and keeps the whole sort free of global data atomics.
__global__ __launch_bounds__(256) void scatter_kernel(const unsigned short* __restrict__ keys,
                                                      const unsigned* __restrict__ breaks,
                                                      const unsigned* __restrict__ blockhist,
                                                      unsigned* __restrict__ order) {
  __shared__ unsigned base_lds[NCELL];  // 16 KB
  __shared__ unsigned ls[256];
  const int tid = threadIdx.x;
  const unsigned myb = blockIdx.x;

  // accumulate totals over all rows; remember partial before own row
  uint4 tot[4], par[4];
#pragma unroll
  for (int g = 0; g < 4; ++g) tot[g] = make_uint4(0u, 0u, 0u, 0u);
#pragma unroll
  for (int g = 0; g < 4; ++g) par[g] = make_uint4(0u, 0u, 0u, 0u);
  for (unsigned bp = 0; bp < NBLK; ++bp) {
    if (bp == myb) {
#pragma unroll
      for (int g = 0; g < 4; ++g) par[g] = tot[g];
    }
    const uint4* rp = (const uint4*)(blockhist + (size_t)bp * NCELL);
#pragma unroll
    for (int g = 0; g < 4; ++g) {
      const uint4 v = rp[tid * 4 + g];
      tot[g].x += v.x; tot[g].y += v.y; tot[g].z += v.z; tot[g].w += v.w;
    }
  }
  unsigned tv[16], pv[16];
#pragma unroll
  for (int g = 0; g < 4; ++g) {
    tv[g * 4 + 0] = tot[g].x; tv[g * 4 + 1] = tot[g].y;
    tv[g * 4 + 2] = tot[g].z; tv[g * 4 + 3] = tot[g].w;
    pv[g * 4 + 0] = par[g].x; pv[g * 4 + 1] = par[g].y;
    pv[g * 4 + 2] = par[g].z; pv[g * 4 + 3] = par[g].w;
  }
  unsigned T = 0u;
#pragma unroll
  for (int j = 0; j < 16; ++j) T += tv[j];
  // exclusive block scan of T over 256 threads
  ls[tid] = T;
  __syncthreads();
  for (int d = 1; d < 256; d <<= 1) {
    const unsigned add = (tid >= d) ? ls[tid - d] : 0u;
    __syncthreads();
    ls[tid] += add;
    __syncthreads();
  }
  unsigned running = ls[tid] - T;  // cellbase of this thread's first cell
  const int c0 = tid * 16;
#pragma unroll
  for (int j = 0; j < 16; ++j) {
    base_lds[c0 + j] = running + pv[j];
    running += tv[j];
  }
  __syncthreads();

  unsigned b1 = NPTS - breaks[0]; if (b1 >= NPTS) b1 = 0u;  // raw=0 -> none -> 0
  unsigned b2 = NPTS - breaks[1]; if (b2 >= NPTS) b2 = 0u;
  const unsigned base = myb * 256u + (unsigned)tid;
#pragma unroll
  for (int k = 0; k < PPT; ++k) {
    const unsigned p = base + (unsigned)k * (NBLK * 256u);
    const unsigned key = keys[p];
    const unsigned pos = atomicAdd(&base_lds[key], 1u);  // LDS atomic -> exact slot
    const unsigned lvl = (p < b1) ? 0u : ((p < b2) ? 1u : 2u);
    order[pos] = p | (lvl << 18);  // NPTS = 2^18
  }
}

// ---------- bilinear sampling helpers ----------
__device__ __forceinline__ void bilinear_weights(int W, float cx, float cy,
                                                 float& w00, float& w01, float& w10, float& w11,
                                                 int& xc0, int& xc1, int& yc0, int& yc1) {
  const float Wm1 = (float)(W - 1);
  const float fx = (cx + 1.0f) * 0.5f * Wm1;
  const float fy = (cy + 1.0f) * 0.5f * Wm1;
  const float x0f = floorf(fx), y0f = floorf(fy);
  const float wx = fx - x0f, wy = fy - y0f;
  const int ix = (int)x0f, iy = (int)y0f;
  const int ix1 = ix + 1, iy1 = iy + 1;
  const bool vx0 = (ix >= 0) && (ix < W);
  const bool vx1 = (ix1 >= 0) && (ix1 < W);
  const bool vy0 = (iy >= 0) && (iy < W);
  const bool vy1 = (iy1 >= 0) && (iy1 < W);
  xc0 = min(max(ix, 0), W - 1);
  xc1 = min(max(ix1, 0), W - 1);
  yc0 = min(max(iy, 0), W - 1);
  yc1 = min(max(iy1, 0), W - 1);
  w00 = (1.0f - wx) * (1.0f - wy) * (float)(vx0 && vy0);
  w01 = wx * (1.0f - wy) * (float)(vx1 && vy0);
  w10 = (1.0f - wx) * wy * (float)(vx0 && vy1);
  w11 = wx * wy * (float)(vx1 && vy1);
}

__device__ __forceinline__ void sample8_t(const __half* __restrict__ pl, int W,
                                          float cx, float cy, int j8, float acc[8]) {
  float w00, w01, w10, w11;
  int xc0, xc1, yc0, yc1;
  bilinear_weights(W, cx, cy, w00, w01, w10, w11, xc0, xc1, yc0, yc1);
  const __half* b00 = pl + ((size_t)(yc0 * W + xc0) * FDIM + j8);
  const __half* b01 = pl + ((size_t)(yc0 * W + xc1) * FDIM + j8);
  const __half* b10 = pl + ((size_t)(yc1 * W + xc0) * FDIM + j8);
  const __half* b11 = pl + ((size_t)(yc1 * W + xc1) * FDIM + j8);
  H8 v00, v01, v10, v11;
  v00.u = *(const uint4*)b00;
  v01.u = *(const uint4*)b01;
  v10.u = *(const uint4*)b10;
  v11.u = *(const uint4*)b11;
#pragma unroll
  for (int k = 0; k < 8; ++k) {
    acc[k] += w00 * __half2float(v00.h[k]) + w01 * __half2float(v01.h[k]) +
              w10 * __half2float(v10.h[k]) + w11 * __half2float(v11.h[k]);
  }
}

__device__ __forceinline__ void sample8_d(const float* __restrict__ pl, int W,
                                          float cx, float cy, int j8, float acc[8]) {
  float w00, w01, w10, w11;
  int xc0, xc1, yc0, yc1;
  bilinear_weights(W, cx, cy, w00, w01, w10, w11, xc0, xc1, yc0, yc1);
  const size_t SS = (size_t)W * W;
  const int i00 = yc0 * W + xc0, i01 = yc0 * W + xc1;
  const int i10 = yc1 * W + xc0, i11 = yc1 * W + xc1;
#pragma unroll
  for (int k = 0; k < 8; ++k) {
    const size_t co = (size_t)(j8 + k) * SS;
    acc[k] += w00 * pl[co + i00] + w01 * pl[co + i01] +
              w10 * pl[co + i10] + w11 * pl[co + i11];
  }
}

struct PlanesH { const __half* p[9]; };
struct PlanesF { const float* p[9]; };

// ---------- main sampling kernel (fp16 transposed planes, sorted order) ----------
#define SAMPLE_BLOCKS (NPTS * 8 / 256)  // 8192
#define XCD_CHUNK (SAMPLE_BLOCKS / 8)   // 1024

__global__ __launch_bounds__(256) void sample_kernel(const float* __restrict__ x,
                                                     const float* __restrict__ scale,
                                                     const unsigned* __restrict__ order,
                                                     PlanesH tp, float* __restrict__ out) {
  const unsigned b = blockIdx.x;
  const unsigned sb = (b & 7u) * XCD_CHUNK + (b >> 3);  // XCD-aware bijective swizzle
  const int t = (int)(sb * 256u + threadIdx.x);
  const int slot = t >> 3;
  const int j8 = (t & 7) * 8;
  const unsigned pk = order[slot];  // 4B, broadcast across the point's 8 threads
  const int p = (int)(pk & 0x3FFFFu);
  const int level = (int)(pk >> 18);
  const float s0 = scale[0], s1 = scale[1], s2 = scale[2];
  const float xs0 = x[p * 3 + 0] * s0;  // 3 MB region, cache-resident
  const float xs1 = x[p * 3 + 1] * s1;
  const float xs2 = x[p * 3 + 2] * s2;
  float acc[8];
#pragma unroll
  for (int k = 0; k < 8; ++k) acc[k] = 0.0f;
  sample8_t(tp.p[0], 512, xs0, xs1, j8, acc);  // xy: (x,y)
  sample8_t(tp.p[1], 512, xs1, xs2, j8, acc);  // yz: (y,z)
  sample8_t(tp.p[2], 512, xs0, xs2, j8, acc);  // xz: (x,z)
  if (level >= 1) {
    sample8_t(tp.p[3], 256, xs0, xs1, j8, acc);
    sample8_t(tp.p[4], 256, xs1, xs2, j8, acc);
    sample8_t(tp.p[5], 256, xs0, xs2, j8, acc);
  }
  if (level >= 2) {
    sample8_t(tp.p[6], 128, xs0, xs1, j8, acc);
    sample8_t(tp.p[7], 128, xs1, xs2, j8, acc);
    sample8_t(tp.p[8], 128, xs0, xs2, j8, acc);
  }
  float* o = out + (size_t)p * FDIM + j8;
  vfloat4 lo = {acc[0], acc[1], acc[2], acc[3]};
  vfloat4 hi = {acc[4], acc[5], acc[6], acc[7]};
  __builtin_nontemporal_store(lo, (vfloat4*)o);
  __builtin_nontemporal_store(hi, (vfloat4*)(o + 4));
}

// ---------- fallback: sample directly from fp32 [C][H][W], unsorted ----------
__global__ __launch_bounds__(256) void sample_kernel_direct(const float* __restrict__ x,
                                                            const float* __restrict__ scale,
                                                            const unsigned* __restrict__ breaks,
                                                            PlanesF tp, float* __restrict__ out) {
  const int t = blockIdx.x * 256 + threadIdx.x;
  const int p = t >> 3;
  const int j8 = (t & 7) * 8;
  const float s0 = scale[0], s1 = scale[1], s2 = scale[2];
  const float xs0 = x[p * 3 + 0] * s0;
  const float xs1 = x[p * 3 + 1] * s1;
  const float xs2 = x[p * 3 + 2] * s2;
  unsigned b1 = breaks[0]; if (b1 >= NPTS) b1 = 0;
  unsigned b2 = breaks[1]; if (b2 >= NPTS) b2 = 0;
  const unsigned pu = (unsigned)p;
  const int level = (pu < b1) ? 0 : ((pu < b2) ? 1 : 2);
  float acc[8];
#pragma unroll
  for (int k = 0; k < 8; ++k) acc[k] = 0.0f;
  sample8_d(tp.p[0], 512, xs0, xs1, j8, acc);
  sample8_d(tp.p[1], 512, xs1, xs2, j8, acc);
  sample8_d(tp.p[2], 512, xs0, xs2, j8, acc);
  if (level >= 1) {
    sample8_d(tp.p[3], 256, xs0, xs1, j8, acc);
    sample8_d(tp.p[4], 256, xs1, xs2, j8, acc);
    sample8_d(tp.p[5], 256, xs0, xs2, j8, acc);
  }
  if (level >= 2) {
    sample8_d(tp.p[6], 128, xs0, xs1, j8, acc);
    sample8_d(tp.p[7], 128, xs1, xs2, j8, acc);
    sample8_d(tp.p[8], 128, xs0, xs2, j8, acc);
  }
  float4* o4 = (float4*)(out + (size_t)p * FDIM + j8);
  o4[0] = make_float4(acc[0], acc[1], acc[2], acc[3]);
  o4[1] = make_float4(acc[4], acc[5], acc[6], acc[7]);
}

extern "C" void kernel_launch(void* const* d_in, const int* in_sizes, int n_in,
                              void* d_out, int out_size, void* d_ws, size_t ws_size,
                              hipStream_t stream) {
  const float* x = (const float*)d_in[0];
  const float* rays_o = (const float*)d_in[1];
  const float* scale = (const float*)d_in[2];
  const float* pl32[9];
  for (int i = 0; i < 9; ++i) pl32[i] = (const float*)d_in[3 + i];
  float* out = (float*)d_out;

  unsigned char* ws = (unsigned char*)d_ws;
  // ws layout: breaks @0 (8B, 0-init) | keys @256 (512 KB) |
  //            blockhist @524544 (1 MB) | order @1573120 (1 MB) | planes @2621696
  unsigned* breaks = (unsigned*)ws;
  unsigned short* keys = (unsigned short*)(ws + 256);
  unsigned* blockhist = (unsigned*)(ws + 256 + (size_t)NPTS * 2);
  unsigned* order = (unsigned*)(ws + 256 + (size_t)NPTS * 2 + (size_t)NBLK * NCELL * 4);
  const size_t planes_off = 256 + (size_t)NPTS * 2 + (size_t)NBLK * NCELL * 4 + (size_t)NPTS * 4;

  const int Ss[3] = {512, 256, 128};
  size_t need = planes_off;
  for (int l = 0; l < 3; ++l) need += 3 * (size_t)Ss[l] * Ss[l] * FDIM * sizeof(__half);

  if (ws_size >= need) {
    (void)hipMemsetAsync(d_ws, 0, 256, stream);  // breaks only

    PlanesH tp;
    TransposeArgs ta;
    size_t off = planes_off;
    int tiles_acc = 0;
    for (int l = 0; l < 3; ++l) {
      const int S = Ss[l];
      const int SS = S * S;
      for (int o = 0; o < 3; ++o) {
        const int i = l * 3 + o;
        __half* dst = (__half*)(ws + off);
        tp.p[i] = dst;
        ta.src[i] = pl32[i];
        ta.dst[i] = dst;
        ta.SS[i] = SS;
        tiles_acc += SS / TPIX;
        ta.tile_hi[i] = tiles_acc;
        off += (size_t)SS * FDIM * sizeof(__half);
      }
    }
    fused_bh_transpose<<<NBLK + tiles_acc, 256, 0, stream>>>(x, rays_o, scale,
                                                             breaks, keys, blockhist, ta);
    scatter_kernel<<<NBLK, 256, 0, stream>>>(keys, breaks, blockhist, order);
    sample_kernel<<<SAMPLE_BLOCKS, 256, 0, stream>>>(x, scale, order, tp, out);
  } else {
    (void)hipMemsetAsync(d_ws, 0xFF, 8, stream);  // sentinel for atomicMin path
    break_kernel<<<256, 256, 0, stream>>>(x, rays_o, scale, breaks);
    PlanesF tf;
    for (int i = 0; i < 9; ++i) tf.p[i] = pl32[i];
    sample_kernel_direct<<<(NPTS * 8) / 256, 256, 0, stream>>>(x, scale, breaks, tf, out);
  }
}